// Round 5
// baseline (6698.781 us; speedup 1.0000x reference)
//
#include <hip/hip_runtime.h>
#include <math.h>

#define BB 2
#define VV 8
#define NQ 336
#define DD 256
#define HEADS 8
#define HD 32
#define FF 1024
#define NL 6
#define BQ (BB*NQ)
#define W_IMG 512
#define H_IMG 512
#define MROWS BQ
#define NWG 256
#define ST 344            // padded LDS stride for attention score rows

struct MKP {
    const float *tgt, *qp, *refpts, *feat0, *feat1, *feat2, *camR, *camT, *camK;
    const float *Wqkv, *bqkv, *Wo, *bo, *ln1g, *ln1b, *Wproj, *bproj, *png, *pnb;
    const float *W1, *b1, *W2, *b2, *ln2g, *ln2b;
    const float *pW0, *pb0, *pW1, *pb1, *pW2, *pb2, *cW, *cb;
    float *out;
    float *x, *xq, *Qp, *Kp, *Vp, *attn_o, *fused, *ffh, *ctmp, *h1b, *h2b, *refb;
    float *fT0, *fT1, *fT2;
    int* bar;             // [0]=count (cacheline), [64]=generation
    int useT;
};

// ---------------- software grid barrier (device-scope atomics, gen/count) ----------------
__device__ __forceinline__ void gbar(int* bar) {
    __syncthreads();
    if (threadIdx.x == 0) {
        __threadfence();   // release: make this block's writes visible device-wide
        int* cnt = bar;
        int* gen = bar + 64;
        int g = __hip_atomic_load(gen, __ATOMIC_RELAXED, __HIP_MEMORY_SCOPE_AGENT);
        int arrived = __hip_atomic_fetch_add(cnt, 1, __ATOMIC_ACQ_REL, __HIP_MEMORY_SCOPE_AGENT);
        if (arrived == NWG - 1) {
            __hip_atomic_store(cnt, 0, __ATOMIC_RELAXED, __HIP_MEMORY_SCOPE_AGENT);
            __hip_atomic_store(gen, g + 1, __ATOMIC_RELEASE, __HIP_MEMORY_SCOPE_AGENT);
        } else {
            while (__hip_atomic_load(gen, __ATOMIC_ACQUIRE, __HIP_MEMORY_SCOPE_AGENT) == g)
                __builtin_amdgcn_s_sleep(2);
        }
        __threadfence();   // acquire: invalidate stale cached lines before consuming
    }
    __syncthreads();
}

// ---------------- transpose one 64x64 tile (job in 0..5375) ----------------
__device__ __forceinline__ void job_transpose(float* sm, int b, const MKP& P) {
    const float* src; float* dst; int HW, ptiles;
    if (b < 4096)      { src = P.feat0; dst = P.fT0; HW = 4096; ptiles = 64; }
    else if (b < 5120) { b -= 4096; src = P.feat1; dst = P.fT1; HW = 1024; ptiles = 16; }
    else               { b -= 5120; src = P.feat2; dst = P.fT2; HW = 256;  ptiles = 4;  }
    int cg_ = b & 3;
    int pt = (b >> 2) % ptiles;
    int bv = (b >> 2) / ptiles;
    int d0 = cg_ * 64, p0 = pt * 64;
    float* tile = sm;                 // [64][65]
    int tid = threadIdx.x;
    int t4 = tid >> 4, t15 = tid & 15;
    __syncthreads();
    #pragma unroll
    for (int pass = 0; pass < 4; ++pass) {
        int d = pass * 16 + t4;
        int p = t15 * 4;
        float4 v = *(const float4*)(src + ((size_t)(bv * DD + d0 + d)) * HW + p0 + p);
        tile[d * 65 + p] = v.x; tile[d * 65 + p + 1] = v.y;
        tile[d * 65 + p + 2] = v.z; tile[d * 65 + p + 3] = v.w;
    }
    __syncthreads();
    #pragma unroll
    for (int pass = 0; pass < 4; ++pass) {
        int p = pass * 16 + t4;
        int d = t15 * 4;
        float4 v = make_float4(tile[d * 65 + p], tile[(d + 1) * 65 + p],
                               tile[(d + 2) * 65 + p], tile[(d + 3) * 65 + p]);
        *(float4*)(dst + ((size_t)bv * HW + p0 + p) * DD + d0 + d) = v;
    }
}

// ---------------- 32x64 GEMM tile job. MODE 0 plain, 1 relu, 2 qkv head-pack ----------------
template <int MODE>
__device__ __forceinline__ void job_gemm(float* sm, const float* __restrict__ A,
                                         const float* __restrict__ W,
                                         const float* __restrict__ bias,
                                         float* __restrict__ C, int Ktot, int kofs, int Kper,
                                         int Nout, int m0, int n0,
                                         float* Qp, float* Kp, float* Vp) {
    float* At = sm;          // [32][34]: At[k][m]
    float* Wt = sm + 1088;   // [32][68]: Wt[k][n]
    int t = threadIdx.x;
    int tx = t & 15, ty = t >> 4;
    int nc = n0 + tx * 4;
    float acc0[4], acc1[4];
    {
        float4 bv = make_float4(0.f, 0.f, 0.f, 0.f);
        if (bias) bv = *(const float4*)(bias + nc);
        acc0[0] = bv.x; acc0[1] = bv.y; acc0[2] = bv.z; acc0[3] = bv.w;
        acc1[0] = bv.x; acc1[1] = bv.y; acc1[2] = bv.z; acc1[3] = bv.w;
    }
    int am = t >> 3, ak4 = (t & 7) * 4;
    int ktiles = Kper >> 5;
    for (int kt = 0; kt < ktiles; ++kt) {
        int kk = kofs + kt * 32;
        __syncthreads();
        {
            float4 v = *(const float4*)(A + (size_t)(m0 + am) * Ktot + kk + ak4);
            At[(ak4 + 0) * 34 + am] = v.x; At[(ak4 + 1) * 34 + am] = v.y;
            At[(ak4 + 2) * 34 + am] = v.z; At[(ak4 + 3) * 34 + am] = v.w;
        }
        #pragma unroll
        for (int s = 0; s < 2; ++s) {
            int idx = t + s * 256;
            int wn = idx >> 3, wk4 = (idx & 7) * 4;
            float4 v = *(const float4*)(W + (size_t)(n0 + wn) * Ktot + kk + wk4);
            Wt[(wk4 + 0) * 68 + wn] = v.x; Wt[(wk4 + 1) * 68 + wn] = v.y;
            Wt[(wk4 + 2) * 68 + wn] = v.z; Wt[(wk4 + 3) * 68 + wn] = v.w;
        }
        __syncthreads();
        #pragma unroll
        for (int k = 0; k < 32; ++k) {
            float2 av = *(const float2*)&At[k * 34 + ty * 2];
            float4 wv = *(const float4*)&Wt[k * 68 + tx * 4];
            acc0[0] = fmaf(av.x, wv.x, acc0[0]); acc0[1] = fmaf(av.x, wv.y, acc0[1]);
            acc0[2] = fmaf(av.x, wv.z, acc0[2]); acc0[3] = fmaf(av.x, wv.w, acc0[3]);
            acc1[0] = fmaf(av.y, wv.x, acc1[0]); acc1[1] = fmaf(av.y, wv.y, acc1[1]);
            acc1[2] = fmaf(av.y, wv.z, acc1[2]); acc1[3] = fmaf(av.y, wv.w, acc1[3]);
        }
    }
    int mr = m0 + ty * 2;
    if (MODE == 2) {
        int kind = nc >> 8;
        float* base = kind == 0 ? Qp : (kind == 1 ? Kp : Vp);
        int h = (nc >> 5) & 7, d4 = nc & 31;
        #pragma unroll
        for (int i = 0; i < 2; ++i) {
            int m = mr + i;
            int b = m / NQ, q = m - b * NQ;
            float* p = base + ((size_t)((b << 3) + h) * NQ + q) * HD + d4;
            float* src = i == 0 ? acc0 : acc1;
            *(float4*)p = make_float4(src[0], src[1], src[2], src[3]);
        }
    } else {
        if (MODE == 1) {
            #pragma unroll
            for (int j = 0; j < 4; ++j) { acc0[j] = fmaxf(acc0[j], 0.f); acc1[j] = fmaxf(acc1[j], 0.f); }
        }
        *(float4*)(C + (size_t)mr * Nout + nc)       = make_float4(acc0[0], acc0[1], acc0[2], acc0[3]);
        *(float4*)(C + (size_t)(mr + 1) * Nout + nc) = make_float4(acc1[0], acc1[1], acc1[2], acc1[3]);
    }
}

// ---------------- attention: 32 q-rows of one (b,h): scores+softmax+PV, all in LDS ----------
__device__ __forceinline__ void job_attn(float* sm, int bh, int qt,
                                         const float* __restrict__ Qp,
                                         const float* __restrict__ Kp,
                                         const float* __restrict__ Vp,
                                         float* __restrict__ attn_o) {
    float* S  = sm;            // [32][ST]
    float* QT = sm + 32 * ST;  // [32][34]: QT[d][q]
    float* KT = QT + 1088;     // [32][68]: KT[d][k]
    int t = threadIdx.x;
    int q0 = qt * 32;
    __syncthreads();
    {
        int q = t >> 3, d4 = (t & 7) * 4;
        int qg = q0 + q;
        float4 v = make_float4(0.f, 0.f, 0.f, 0.f);
        if (qg < NQ) v = *(const float4*)(Qp + ((size_t)bh * NQ + qg) * HD + d4);
        const float sc = 0.17677669529663687f;
        QT[(d4 + 0) * 34 + q] = v.x * sc; QT[(d4 + 1) * 34 + q] = v.y * sc;
        QT[(d4 + 2) * 34 + q] = v.z * sc; QT[(d4 + 3) * 34 + q] = v.w * sc;
    }
    int tx = t & 15, ty = t >> 4;
    for (int kt = 0; kt < 6; ++kt) {
        __syncthreads();
        #pragma unroll
        for (int s = 0; s < 2; ++s) {
            int idx = t + s * 256;
            int k = idx >> 3, d4 = (idx & 7) * 4;
            int kg = kt * 64 + k;
            float4 v = make_float4(0.f, 0.f, 0.f, 0.f);
            if (kg < NQ) v = *(const float4*)(Kp + ((size_t)bh * NQ + kg) * HD + d4);
            KT[(d4 + 0) * 68 + k] = v.x; KT[(d4 + 1) * 68 + k] = v.y;
            KT[(d4 + 2) * 68 + k] = v.z; KT[(d4 + 3) * 68 + k] = v.w;
        }
        __syncthreads();
        float4 a0 = make_float4(0.f, 0.f, 0.f, 0.f);
        float4 a1 = make_float4(0.f, 0.f, 0.f, 0.f);
        #pragma unroll
        for (int d = 0; d < 32; ++d) {
            float2 qv = *(const float2*)&QT[d * 34 + ty * 2];
            float4 kv = *(const float4*)&KT[d * 68 + tx * 4];
            a0.x = fmaf(qv.x, kv.x, a0.x); a0.y = fmaf(qv.x, kv.y, a0.y);
            a0.z = fmaf(qv.x, kv.z, a0.z); a0.w = fmaf(qv.x, kv.w, a0.w);
            a1.x = fmaf(qv.y, kv.x, a1.x); a1.y = fmaf(qv.y, kv.y, a1.y);
            a1.z = fmaf(qv.y, kv.z, a1.z); a1.w = fmaf(qv.y, kv.w, a1.w);
        }
        int k4g = kt * 64 + tx * 4;
        if (k4g < ST) {
            int qq = ty * 2;
            *(float4*)&S[qq * ST + k4g] = a0;
            *(float4*)&S[(qq + 1) * ST + k4g] = a1;
        }
    }
    __syncthreads();
    {   // softmax: 8 lanes per row, 42 cols each (8*42 = 336)
        int r = t >> 3, l8 = t & 7;
        float* row = &S[r * ST];
        float m = -1e30f;
        #pragma unroll
        for (int i = 0; i < 42; ++i) m = fmaxf(m, row[l8 + i * 8]);
        m = fmaxf(m, __shfl_xor(m, 1)); m = fmaxf(m, __shfl_xor(m, 2)); m = fmaxf(m, __shfl_xor(m, 4));
        float ssum = 0.f;
        #pragma unroll
        for (int i = 0; i < 42; ++i) {
            float e = expf(row[l8 + i * 8] - m);
            row[l8 + i * 8] = e;
            ssum += e;
        }
        ssum += __shfl_xor(ssum, 1); ssum += __shfl_xor(ssum, 2); ssum += __shfl_xor(ssum, 4);
        float inv = 1.f / ssum;
        #pragma unroll
        for (int i = 0; i < 42; ++i) row[l8 + i * 8] *= inv;
    }
    __syncthreads();
    {   // PV
        float* Vt = sm + 32 * ST;   // [64][36]
        int d4 = (t & 7) * 4, q = t >> 3;
        float4 o = make_float4(0.f, 0.f, 0.f, 0.f);
        for (int kt2 = 0; kt2 < 6; ++kt2) {
            __syncthreads();
            #pragma unroll
            for (int s = 0; s < 2; ++s) {
                int idx = t + s * 256;
                int k = idx >> 3, vd4 = (idx & 7) * 4;
                int kg = kt2 * 64 + k;
                float4 v = make_float4(0.f, 0.f, 0.f, 0.f);
                if (kg < NQ) v = *(const float4*)(Vp + ((size_t)bh * NQ + kg) * HD + vd4);
                *(float4*)&Vt[k * 36 + vd4] = v;
            }
            __syncthreads();
            int klim = (kt2 == 5) ? 24 : 64;      // cols >= 344 would read past the padded row
            for (int kk = 0; kk < klim; ++kk) {
                float p = S[q * ST + kt2 * 64 + kk];
                float4 v = *(const float4*)&Vt[kk * 36 + d4];
                o.x = fmaf(p, v.x, o.x); o.y = fmaf(p, v.y, o.y);
                o.z = fmaf(p, v.z, o.z); o.w = fmaf(p, v.w, o.w);
            }
        }
        int qg = q0 + q;
        if (qg < NQ) {
            int b = bh >> 3, h = bh & 7;
            *(float4*)(attn_o + ((size_t)(b * NQ + qg)) * DD + h * HD + d4) = o;
        }
    }
}

// ---------------- residual + LayerNorm over np partials, 4 rows; optional xq ----------------
__device__ __forceinline__ void job_ln(float* sm, int job, int np, float* __restrict__ x,
                                       const float* __restrict__ C,
                                       const float* __restrict__ gam,
                                       const float* __restrict__ bet,
                                       const float* __restrict__ qp, float* __restrict__ xq) {
    float* redS  = sm;        // [4][4]
    float* redS2 = sm + 16;   // [4][4]
    float* mu    = sm + 32;   // [4]
    float* ri    = sm + 36;   // [4]
    int r0 = job * 4;
    int j = threadIdx.x;
    __syncthreads();
    float val[4];
    #pragma unroll
    for (int r = 0; r < 4; ++r) {
        float a = x[(size_t)(r0 + r) * DD + j];
        for (int p = 0; p < np; ++p)
            a += C[(size_t)p * MROWS * DD + (size_t)(r0 + r) * DD + j];
        val[r] = a;
    }
    float s[4], s2[4];
    #pragma unroll
    for (int r = 0; r < 4; ++r) { s[r] = val[r]; s2[r] = val[r] * val[r]; }
    #pragma unroll
    for (int o = 32; o > 0; o >>= 1) {
        #pragma unroll
        for (int r = 0; r < 4; ++r) {
            s[r]  += __shfl_xor(s[r],  o);
            s2[r] += __shfl_xor(s2[r], o);
        }
    }
    int wid = j >> 6, lane = j & 63;
    if (lane == 0) {
        #pragma unroll
        for (int r = 0; r < 4; ++r) { redS[r * 4 + wid] = s[r]; redS2[r * 4 + wid] = s2[r]; }
    }
    __syncthreads();
    if (j < 4) {
        int r = j;
        float ts  = redS[r * 4 + 0]  + redS[r * 4 + 1]  + redS[r * 4 + 2]  + redS[r * 4 + 3];
        float ts2 = redS2[r * 4 + 0] + redS2[r * 4 + 1] + redS2[r * 4 + 2] + redS2[r * 4 + 3];
        float mean = ts * (1.f / DD);
        float var = ts2 * (1.f / DD) - mean * mean;
        mu[r] = mean;
        ri[r] = rsqrtf(var + 1e-5f);
    }
    __syncthreads();
    float g = gam[j], be = bet[j];
    #pragma unroll
    for (int r = 0; r < 4; ++r) {
        float o = (val[r] - mu[r]) * ri[r] * g + be;
        x[(size_t)(r0 + r) * DD + j] = o;
        if (qp) xq[(size_t)(r0 + r) * DD + j] = o + qp[(size_t)(r0 + r) * DD + j];
    }
}

// ---------------- bilinear sample helper ----------------
template <bool TRANSPOSED>
__device__ __forceinline__ float sample_level(const float* __restrict__ f, int bv, int Hh,
                                              float un, float vn, int dth) {
    int Ww = Hh;
    float xx = (un + 1.f) * Ww * 0.5f - 0.5f;
    float yy = (vn + 1.f) * Hh * 0.5f - 0.5f;
    float x0f = floorf(xx), y0f = floorf(yy);
    int ix0 = (int)x0f, iy0 = (int)y0f;
    float wx1 = xx - x0f, wx0 = 1.f - wx1;
    float wy1 = yy - y0f, wy0 = 1.f - wy1;
    float s = 0.f;
#define TAP(IX, IY, W)                                                           \
    {                                                                            \
        int ix = (IX), iy = (IY);                                                \
        if (ix >= 0 && ix < Ww && iy >= 0 && iy < Hh) {                          \
            float v;                                                             \
            if (TRANSPOSED)                                                      \
                v = f[((size_t)bv * Hh * Ww + (size_t)iy * Ww + ix) * DD + dth]; \
            else                                                                 \
                v = f[(((size_t)bv * DD + dth) * Hh + iy) * Ww + ix];            \
            s = fmaf((W), v, s);                                                 \
        }                                                                        \
    }
    TAP(ix0,     iy0,     wy0 * wx0)
    TAP(ix0 + 1, iy0,     wy0 * wx1)
    TAP(ix0,     iy0 + 1, wy1 * wx0)
    TAP(ix0 + 1, iy0 + 1, wy1 * wx1)
#undef TAP
    return s;
}

// ---------------- project + sample + mask-fuse, 4 rows ----------------
__device__ __forceinline__ void job_sample(float* sm, int job, const MKP& P) {
    float* sg = sm;   // [4][8][3]
    int t = threadIdx.x;
    int r0j = job * 4;
    __syncthreads();
    if (t < 32) {
        int rr = t >> 3, v = t & 7;
        int row = r0j + rr;
        int b = row / NQ;
        int bv = b * VV + v;
        const float* r = P.refb + (size_t)row * 3;
        const float* R = P.camR + (size_t)bv * 9;
        const float* T = P.camT + (size_t)bv * 3;
        const float* K = P.camK + (size_t)bv * 9;
        float p0 = R[0] * r[0] + R[1] * r[1] + R[2] * r[2] + T[0];
        float p1 = R[3] * r[0] + R[4] * r[1] + R[5] * r[2] + T[1];
        float p2 = R[6] * r[0] + R[7] * r[1] + R[8] * r[2] + T[2];
        float z = fmaxf(p2, 0.1f);
        float u  = p0 * K[0] / z + K[2];
        float vv = p1 * K[4] / z + K[5];
        float un = 2.f * u  / (float)(W_IMG - 1) - 1.f;
        float vn = 2.f * vv / (float)(H_IMG - 1) - 1.f;
        bool m = (un > -1.f) && (un < 1.f) && (vn > -1.f) && (vn < 1.f) && (p2 > 0.f);
        sg[(rr * 8 + v) * 3 + 0] = un;
        sg[(rr * 8 + v) * 3 + 1] = vn;
        sg[(rr * 8 + v) * 3 + 2] = m ? 1.f : 0.f;
    }
    __syncthreads();
    for (int rr = 0; rr < 4; ++rr) {
        int row = r0j + rr;
        int b = row / NQ;
        float acc = 0.f, cnt = 0.f;
        for (int v = 0; v < VV; ++v) {
            float m = sg[(rr * 8 + v) * 3 + 2];
            if (m == 0.f) continue;
            cnt += 1.f;
            float un = sg[(rr * 8 + v) * 3 + 0], vn = sg[(rr * 8 + v) * 3 + 1];
            int bv = b * VV + v;
            float ms;
            if (P.useT)
                ms = sample_level<true>(P.fT0, bv, 64, un, vn, t)
                   + sample_level<true>(P.fT1, bv, 32, un, vn, t)
                   + sample_level<true>(P.fT2, bv, 16, un, vn, t);
            else
                ms = sample_level<false>(P.feat0, bv, 64, un, vn, t)
                   + sample_level<false>(P.feat1, bv, 32, un, vn, t)
                   + sample_level<false>(P.feat2, bv, 16, un, vn, t);
            acc += ms * (1.f / 3.f);
        }
        P.fused[(size_t)row * DD + t] = acc / fmaxf(cnt, 1.f);
    }
}

// ---------------- pose delta + cls for 4 rows (one wave per row) ----------------
__device__ __forceinline__ void job_pose_cls(int job, const MKP& P, float* outp) {
    int t = threadIdx.x;
    int wv = t >> 6, lane = t & 63;
    int row = job * 4 + wv;
    float v0 = 0.f, v1 = 0.f, v2 = 0.f, v3 = 0.f;
    for (int c = lane; c < DD; c += 64) {
        float hv = P.h2b[(size_t)row * DD + c];
        float xv = P.x[(size_t)row * DD + c];
        v0 = fmaf(hv, P.pW2[c], v0);
        v1 = fmaf(hv, P.pW2[DD + c], v1);
        v2 = fmaf(hv, P.pW2[2 * DD + c], v2);
        v3 = fmaf(xv, P.cW[c], v3);
    }
    #pragma unroll
    for (int o = 32; o > 0; o >>= 1) {
        v0 += __shfl_xor(v0, o); v1 += __shfl_xor(v1, o);
        v2 += __shfl_xor(v2, o); v3 += __shfl_xor(v3, o);
    }
    if (lane == 0) {
        float r0 = P.refb[(size_t)row * 3 + 0] + v0 + P.pb2[0];
        float r1 = P.refb[(size_t)row * 3 + 1] + v1 + P.pb2[1];
        float r2 = P.refb[(size_t)row * 3 + 2] + v2 + P.pb2[2];
        float cl = v3 + P.cb[0];
        P.refb[(size_t)row * 3 + 0] = r0;
        P.refb[(size_t)row * 3 + 1] = r1;
        P.refb[(size_t)row * 3 + 2] = r2;
        outp[(size_t)row * 4 + 0] = cl;
        outp[(size_t)row * 4 + 1] = r0;
        outp[(size_t)row * 4 + 2] = r1;
        outp[(size_t)row * 4 + 3] = r2;
    }
}

// ==================== the persistent megakernel ====================
__global__ __launch_bounds__(256) void mega(MKP P) {
    __shared__ float sm[14400];   // 57.6 KB: max over phase needs
    int wg = blockIdx.x;
    int t = threadIdx.x;

    // ---- init: transpose features + x/xq/refb ----
    if (P.useT) {
        for (int j = wg; j < 5376; j += NWG) job_transpose(sm, j, P);
    }
    for (int i = wg * 256 + t; i < BQ * DD / 4; i += NWG * 256) {
        float4 tv = ((const float4*)P.tgt)[i];
        float4 qv = ((const float4*)P.qp)[i];
        ((float4*)P.x)[i] = tv;
        ((float4*)P.xq)[i] = make_float4(tv.x + qv.x, tv.y + qv.y, tv.z + qv.z, tv.w + qv.w);
    }
    for (int i = wg * 256 + t; i < BQ * 3; i += NWG * 256) P.refb[i] = P.refpts[i];
    gbar(P.bar);

    for (int l = 0; l < NL; ++l) {
        const float* Wqkv_l = P.Wqkv + (size_t)l * 3 * DD * DD;
        const float* bqkv_l = P.bqkv + (size_t)l * 3 * DD;
        const float* Wo_l   = P.Wo   + (size_t)l * DD * DD;
        const float* bo_l   = P.bo   + (size_t)l * DD;
        const float* Wpj_l  = P.Wproj+ (size_t)l * DD * DD;
        const float* bpj_l  = P.bproj+ (size_t)l * DD;
        const float* W1_l   = P.W1   + (size_t)l * FF * DD;
        const float* b1_l   = P.b1   + (size_t)l * FF;
        const float* W2_l   = P.W2   + (size_t)l * DD * FF;
        const float* b2_l   = P.b2   + (size_t)l * DD;

        // PH_A: qkv (252) + pose0 of layer l-1 (84)
        {
            int nj = 252 + (l > 0 ? 84 : 0);
            for (int j = wg; j < nj; j += NWG) {
                if (j < 252) {
                    int mrow = j % 21, ncol = j / 21;
                    const float* A = (ncol < 8) ? P.xq : P.x;
                    job_gemm<2>(sm, A, Wqkv_l, bqkv_l, nullptr, DD, 0, DD, 0,
                                mrow * 32, ncol * 64, P.Qp, P.Kp, P.Vp);
                } else {
                    int jj = j - 252;
                    job_gemm<1>(sm, P.x, P.pW0, P.pb0, P.h1b, DD, 0, DD, DD,
                                (jj % 21) * 32, (jj / 21) * 64, nullptr, nullptr, nullptr);
                }
            }
        }
        gbar(P.bar);
        // PH_B: attention (176) + pose1 of l-1 (84)
        {
            int nj = 176 + (l > 0 ? 84 : 0);
            for (int j = wg; j < nj; j += NWG) {
                if (j < 176) {
                    job_attn(sm, j % 16, j / 16, P.Qp, P.Kp, P.Vp, P.attn_o);
                } else {
                    int jj = j - 176;
                    job_gemm<1>(sm, P.h1b, P.pW1, P.pb1, P.h2b, DD, 0, DD, DD,
                                (jj % 21) * 32, (jj / 21) * 64, nullptr, nullptr, nullptr);
                }
            }
        }
        gbar(P.bar);
        // PH_C: o-proj (84) + pose_cls of l-1 (168)
        {
            int nj = 84 + (l > 0 ? 168 : 0);
            for (int j = wg; j < nj; j += NWG) {
                if (j < 84) {
                    job_gemm<0>(sm, P.attn_o, Wo_l, bo_l, P.ctmp, DD, 0, DD, DD,
                                (j % 21) * 32, (j / 21) * 64, nullptr, nullptr, nullptr);
                } else {
                    job_pose_cls(j - 84, P, P.out + (size_t)(l - 1) * BQ * 4);
                }
            }
        }
        gbar(P.bar);
        // PH_D: ln1 (168) + sample (168, uses refb updated in PH_C)
        {
            for (int j = wg; j < 336; j += NWG) {
                if (j < 168)
                    job_ln(sm, j, 1, P.x, P.ctmp, P.ln1g + (size_t)l * DD,
                           P.ln1b + (size_t)l * DD, nullptr, nullptr);
                else
                    job_sample(sm, j - 168, P);
            }
        }
        gbar(P.bar);
        // PH_E: proj-GEMM (84)
        {
            for (int j = wg; j < 84; j += NWG)
                job_gemm<0>(sm, P.fused, Wpj_l, bpj_l, P.ctmp, DD, 0, DD, DD,
                            (j % 21) * 32, (j / 21) * 64, nullptr, nullptr, nullptr);
        }
        gbar(P.bar);
        // PH_F: ln_pn (168)
        {
            for (int j = wg; j < 168; j += NWG)
                job_ln(sm, j, 1, P.x, P.ctmp, P.png + (size_t)l * DD,
                       P.pnb + (size_t)l * DD, nullptr, nullptr);
        }
        gbar(P.bar);
        // PH_G: ffn1 (336)
        {
            for (int j = wg; j < 336; j += NWG)
                job_gemm<1>(sm, P.x, W1_l, b1_l, P.ffh, DD, 0, DD, FF,
                            (j % 21) * 32, (j / 21) * 64, nullptr, nullptr, nullptr);
        }
        gbar(P.bar);
        // PH_H: ffn2 k-split x4 (336)
        {
            for (int j = wg; j < 336; j += NWG) {
                int kz = j / 84, r = j % 84;
                job_gemm<0>(sm, P.ffh, W2_l, kz == 0 ? b2_l : nullptr,
                            P.ctmp + (size_t)kz * MROWS * DD, FF, kz * 256, 256, DD,
                            (r % 21) * 32, (r / 21) * 64, nullptr, nullptr, nullptr);
            }
        }
        gbar(P.bar);
        // PH_I: ln2 (168) + xq = x + query_pos
        {
            for (int j = wg; j < 168; j += NWG)
                job_ln(sm, j, 4, P.x, P.ctmp, P.ln2g + (size_t)l * DD,
                       P.ln2b + (size_t)l * DD, P.qp, P.xq);
        }
        gbar(P.bar);
    }
    // tail: pose head of layer NL-1
    for (int j = wg; j < 84; j += NWG)
        job_gemm<1>(sm, P.x, P.pW0, P.pb0, P.h1b, DD, 0, DD, DD,
                    (j % 21) * 32, (j / 21) * 64, nullptr, nullptr, nullptr);
    gbar(P.bar);
    for (int j = wg; j < 84; j += NWG)
        job_gemm<1>(sm, P.h1b, P.pW1, P.pb1, P.h2b, DD, 0, DD, DD,
                    (j % 21) * 32, (j / 21) * 64, nullptr, nullptr, nullptr);
    gbar(P.bar);
    for (int j = wg; j < 168; j += NWG)
        job_pose_cls(j, P, P.out + (size_t)(NL - 1) * BQ * 4);
}

extern "C" void kernel_launch(void* const* d_in, const int* in_sizes, int n_in,
                              void* d_out, int out_size, void* d_ws, size_t ws_size,
                              hipStream_t stream) {
    MKP P;
    P.tgt    = (const float*)d_in[0];
    P.qp     = (const float*)d_in[1];
    P.refpts = (const float*)d_in[2];
    P.feat0  = (const float*)d_in[3];
    P.feat1  = (const float*)d_in[4];
    P.feat2  = (const float*)d_in[5];
    P.camR   = (const float*)d_in[6];
    P.camT   = (const float*)d_in[7];
    P.camK   = (const float*)d_in[8];
    P.Wqkv   = (const float*)d_in[9];
    P.bqkv   = (const float*)d_in[10];
    P.Wo     = (const float*)d_in[11];
    P.bo     = (const float*)d_in[12];
    P.ln1g   = (const float*)d_in[13];
    P.ln1b   = (const float*)d_in[14];
    P.Wproj  = (const float*)d_in[15];
    P.bproj  = (const float*)d_in[16];
    P.png    = (const float*)d_in[17];
    P.pnb    = (const float*)d_in[18];
    P.W1     = (const float*)d_in[19];
    P.b1     = (const float*)d_in[20];
    P.W2     = (const float*)d_in[21];
    P.b2     = (const float*)d_in[22];
    P.ln2g   = (const float*)d_in[23];
    P.ln2b   = (const float*)d_in[24];
    P.pW0    = (const float*)d_in[25];
    P.pb0    = (const float*)d_in[26];
    P.pW1    = (const float*)d_in[27];
    P.pb1    = (const float*)d_in[28];
    P.pW2    = (const float*)d_in[29];
    P.pb2    = (const float*)d_in[30];
    P.cW     = (const float*)d_in[31];
    P.cb     = (const float*)d_in[32];
    P.out    = (float*)d_out;

    float* w = (float*)d_ws;
    size_t off = 0;
    auto alloc = [&](size_t n) { float* p = w + off; off += n; return p; };
    P.bar    = (int*)alloc(256);          // barrier state: count @0, gen @64 (ints)
    P.x      = alloc((size_t)BQ * DD);
    P.xq     = alloc((size_t)BQ * DD);
    P.Qp     = alloc((size_t)BB * HEADS * NQ * HD);
    P.Kp     = alloc((size_t)BB * HEADS * NQ * HD);
    P.Vp     = alloc((size_t)BB * HEADS * NQ * HD);
    P.attn_o = alloc((size_t)BQ * DD);
    P.fused  = alloc((size_t)BQ * DD);
    P.ffh    = alloc((size_t)BQ * FF);
    P.ctmp   = alloc((size_t)4 * BQ * DD);
    P.h1b    = alloc((size_t)BQ * DD);
    P.h2b    = alloc((size_t)BQ * DD);
    P.refb   = alloc((size_t)BQ * 3 + 64);
    size_t base_floats = off;
    size_t featT_floats = (size_t)BB * VV * DD * (64 * 64 + 32 * 32 + 16 * 16);
    P.useT = (ws_size >= (base_floats + featT_floats) * sizeof(float)) ? 1 : 0;
    P.fT0 = nullptr; P.fT1 = nullptr; P.fT2 = nullptr;
    if (P.useT) {
        P.fT0 = alloc((size_t)BB * VV * 64 * 64 * DD);
        P.fT1 = alloc((size_t)BB * VV * 32 * 32 * DD);
        P.fT2 = alloc((size_t)BB * VV * 16 * 16 * DD);
    }

    // zero the barrier state (d_ws is poisoned 0xAA before every timed launch)
    hipMemsetAsync(P.bar, 0, 256 * sizeof(float), stream);
    mega<<<dim3(NWG), dim3(256), 0, stream>>>(P);
}

// Round 6
// 2625.720 us; speedup vs baseline: 2.5512x; 2.5512x over previous
//
#include <hip/hip_runtime.h>
#include <math.h>

#define BB 2
#define VV 8
#define NQ 336
#define DD 256
#define HEADS 8
#define HD 32
#define FF 1024
#define NL 6
#define BQ (BB*NQ)
#define W_IMG 512
#define H_IMG 512
#define ST 344            // padded LDS stride for attention score rows

// ---------------- merged LDS-tiled transpose: (BV,D,H,W) -> (BV,H,W,D) for all 3 levels ----
__global__ __launch_bounds__(256) void transpose_all(const float* __restrict__ f0,
                                                     const float* __restrict__ f1,
                                                     const float* __restrict__ f2,
                                                     float* __restrict__ o0,
                                                     float* __restrict__ o1,
                                                     float* __restrict__ o2) {
    int b = blockIdx.x;
    const float* src; float* dst; int HW, ptiles;
    if (b < 4096)      { src = f0; dst = o0; HW = 4096; ptiles = 64; }
    else if (b < 5120) { b -= 4096; src = f1; dst = o1; HW = 1024; ptiles = 16; }
    else               { b -= 5120; src = f2; dst = o2; HW = 256;  ptiles = 4;  }
    int cg = b & 3;
    int pt = (b >> 2) % ptiles;
    int bv = (b >> 2) / ptiles;
    int d0 = cg * 64, p0 = pt * 64;
    __shared__ float tile[64][65];
    int tid = threadIdx.x;
    int t4 = tid >> 4, t15 = tid & 15;
    #pragma unroll
    for (int pass = 0; pass < 4; ++pass) {
        int d = pass * 16 + t4;
        int p = t15 * 4;
        float4 v = *(const float4*)(src + ((size_t)(bv * DD + d0 + d)) * HW + p0 + p);
        tile[d][p] = v.x; tile[d][p + 1] = v.y; tile[d][p + 2] = v.z; tile[d][p + 3] = v.w;
    }
    __syncthreads();
    #pragma unroll
    for (int pass = 0; pass < 4; ++pass) {
        int p = pass * 16 + t4;
        int d = t15 * 4;
        float4 v = make_float4(tile[d][p], tile[d + 1][p], tile[d + 2][p], tile[d + 3][p]);
        *(float4*)(dst + ((size_t)bv * HW + p0 + p) * DD + d0 + d) = v;
    }
}

// ---------------- init: x = tgt, xq = tgt + qp, refb = refpts ----------------
__global__ __launch_bounds__(256) void init_k(const float* __restrict__ tgt,
                                              const float* __restrict__ qp,
                                              const float* __restrict__ refpts,
                                              float* __restrict__ x,
                                              float* __restrict__ xq,
                                              float* __restrict__ refb) {
    int i = blockIdx.x * 256 + threadIdx.x;
    float4 tv = ((const float4*)tgt)[i];
    float4 qv = ((const float4*)qp)[i];
    ((float4*)x)[i] = tv;
    ((float4*)xq)[i] = make_float4(tv.x + qv.x, tv.y + qv.y, tv.z + qv.z, tv.w + qv.w);
    if (i < BQ * 3) refb[i] = refpts[i];
}

// ---------------- QKV: tiled GEMM 32x64, head-packed Q/K/V output. grid (21, 12) ----------
__global__ __launch_bounds__(256) void qkv_tile(const float* __restrict__ Aq,
                                                const float* __restrict__ Ax,
                                                const float* __restrict__ W,
                                                const float* __restrict__ bias,
                                                float* __restrict__ Qp,
                                                float* __restrict__ Kp,
                                                float* __restrict__ Vp) {
    __shared__ float At[32][34];
    __shared__ float Wt[32][68];
    int t = threadIdx.x;
    int m0 = blockIdx.x * 32;
    int n0 = blockIdx.y * 64;
    const float* A = (blockIdx.y < 8) ? Aq : Ax;
    int tx = t & 15, ty = t >> 4;
    int nc = n0 + tx * 4;
    float acc0[4], acc1[4];
    {
        float4 bv = *(const float4*)(bias + nc);
        acc0[0] = bv.x; acc0[1] = bv.y; acc0[2] = bv.z; acc0[3] = bv.w;
        acc1[0] = bv.x; acc1[1] = bv.y; acc1[2] = bv.z; acc1[3] = bv.w;
    }
    int am = t >> 3, ak4 = (t & 7) * 4;
    for (int kt = 0; kt < 8; ++kt) {
        int kk = kt * 32;
        __syncthreads();
        {
            float4 v = *(const float4*)(A + (size_t)(m0 + am) * DD + kk + ak4);
            At[ak4 + 0][am] = v.x; At[ak4 + 1][am] = v.y;
            At[ak4 + 2][am] = v.z; At[ak4 + 3][am] = v.w;
        }
        #pragma unroll
        for (int s = 0; s < 2; ++s) {
            int idx = t + s * 256;
            int wn = idx >> 3, wk4 = (idx & 7) * 4;
            float4 v = *(const float4*)(W + (size_t)(n0 + wn) * DD + kk + wk4);
            Wt[wk4 + 0][wn] = v.x; Wt[wk4 + 1][wn] = v.y;
            Wt[wk4 + 2][wn] = v.z; Wt[wk4 + 3][wn] = v.w;
        }
        __syncthreads();
        #pragma unroll
        for (int k = 0; k < 32; ++k) {
            float2 av = *(const float2*)&At[k][ty * 2];
            float4 wv = *(const float4*)&Wt[k][tx * 4];
            acc0[0] = fmaf(av.x, wv.x, acc0[0]); acc0[1] = fmaf(av.x, wv.y, acc0[1]);
            acc0[2] = fmaf(av.x, wv.z, acc0[2]); acc0[3] = fmaf(av.x, wv.w, acc0[3]);
            acc1[0] = fmaf(av.y, wv.x, acc1[0]); acc1[1] = fmaf(av.y, wv.y, acc1[1]);
            acc1[2] = fmaf(av.y, wv.z, acc1[2]); acc1[3] = fmaf(av.y, wv.w, acc1[3]);
        }
    }
    int mr = m0 + ty * 2;
    int kind = nc >> 8;
    float* base = kind == 0 ? Qp : (kind == 1 ? Kp : Vp);
    int h = (nc >> 5) & 7, d4 = nc & 31;
    #pragma unroll
    for (int i = 0; i < 2; ++i) {
        int m = mr + i;
        int b = m / NQ, q = m - b * NQ;
        float* p = base + ((size_t)((b << 3) + h) * NQ + q) * HD + d4;
        float* src = i == 0 ? acc0 : acc1;
        *(float4*)p = make_float4(src[0], src[1], src[2], src[3]);
    }
}

// ---------------- fused attention: scores+softmax+PV for 32 q-rows of one (b,h) -----------
// grid: 176 = 16 bh * 11 qtiles (of 32 rows)
__global__ __launch_bounds__(256) void attn_fused(const float* __restrict__ Qp,
                                                  const float* __restrict__ Kp,
                                                  const float* __restrict__ Vp,
                                                  float* __restrict__ attn_o) {
    __shared__ float sm[32 * ST + 32 * 34 + 32 * 68];
    float* S  = sm;            // [32][ST]
    float* QT = sm + 32 * ST;  // [32][34]: QT[d][q]
    float* KT = QT + 1088;     // [32][68]: KT[d][k]
    int bh = blockIdx.x & 15, qt = blockIdx.x >> 4;
    int t = threadIdx.x;
    int q0 = qt * 32;
    {
        int q = t >> 3, d4 = (t & 7) * 4;
        int qg = q0 + q;
        float4 v = make_float4(0.f, 0.f, 0.f, 0.f);
        if (qg < NQ) v = *(const float4*)(Qp + ((size_t)bh * NQ + qg) * HD + d4);
        const float sc = 0.17677669529663687f;
        QT[(d4 + 0) * 34 + q] = v.x * sc; QT[(d4 + 1) * 34 + q] = v.y * sc;
        QT[(d4 + 2) * 34 + q] = v.z * sc; QT[(d4 + 3) * 34 + q] = v.w * sc;
    }
    int tx = t & 15, ty = t >> 4;
    for (int kt = 0; kt < 6; ++kt) {
        __syncthreads();
        #pragma unroll
        for (int s = 0; s < 2; ++s) {
            int idx = t + s * 256;
            int k = idx >> 3, d4 = (idx & 7) * 4;
            int kg = kt * 64 + k;
            float4 v = make_float4(0.f, 0.f, 0.f, 0.f);
            if (kg < NQ) v = *(const float4*)(Kp + ((size_t)bh * NQ + kg) * HD + d4);
            KT[(d4 + 0) * 68 + k] = v.x; KT[(d4 + 1) * 68 + k] = v.y;
            KT[(d4 + 2) * 68 + k] = v.z; KT[(d4 + 3) * 68 + k] = v.w;
        }
        __syncthreads();
        float4 a0 = make_float4(0.f, 0.f, 0.f, 0.f);
        float4 a1 = make_float4(0.f, 0.f, 0.f, 0.f);
        #pragma unroll
        for (int d = 0; d < 32; ++d) {
            float2 qv = *(const float2*)&QT[d * 34 + ty * 2];
            float4 kv = *(const float4*)&KT[d * 68 + tx * 4];
            a0.x = fmaf(qv.x, kv.x, a0.x); a0.y = fmaf(qv.x, kv.y, a0.y);
            a0.z = fmaf(qv.x, kv.z, a0.z); a0.w = fmaf(qv.x, kv.w, a0.w);
            a1.x = fmaf(qv.y, kv.x, a1.x); a1.y = fmaf(qv.y, kv.y, a1.y);
            a1.z = fmaf(qv.y, kv.z, a1.z); a1.w = fmaf(qv.y, kv.w, a1.w);
        }
        int k4g = kt * 64 + tx * 4;
        if (k4g < ST) {
            int qq = ty * 2;
            *(float4*)&S[qq * ST + k4g] = a0;
            *(float4*)&S[(qq + 1) * ST + k4g] = a1;
        }
    }
    __syncthreads();
    {   // softmax: 8 lanes per row, 42 cols each
        int r = t >> 3, l8 = t & 7;
        float* row = &S[r * ST];
        float m = -1e30f;
        #pragma unroll
        for (int i = 0; i < 42; ++i) m = fmaxf(m, row[l8 + i * 8]);
        m = fmaxf(m, __shfl_xor(m, 1)); m = fmaxf(m, __shfl_xor(m, 2)); m = fmaxf(m, __shfl_xor(m, 4));
        float ssum = 0.f;
        #pragma unroll
        for (int i = 0; i < 42; ++i) {
            float e = expf(row[l8 + i * 8] - m);
            row[l8 + i * 8] = e;
            ssum += e;
        }
        ssum += __shfl_xor(ssum, 1); ssum += __shfl_xor(ssum, 2); ssum += __shfl_xor(ssum, 4);
        float inv = 1.f / ssum;
        #pragma unroll
        for (int i = 0; i < 42; ++i) row[l8 + i * 8] *= inv;
    }
    __syncthreads();
    {   // PV
        float* Vt = sm + 32 * ST;   // [64][36] (overlaps QT/KT, done with them)
        int d4 = (t & 7) * 4, q = t >> 3;
        float4 o = make_float4(0.f, 0.f, 0.f, 0.f);
        for (int kt2 = 0; kt2 < 6; ++kt2) {
            __syncthreads();
            #pragma unroll
            for (int s = 0; s < 2; ++s) {
                int idx = t + s * 256;
                int k = idx >> 3, vd4 = (idx & 7) * 4;
                int kg = kt2 * 64 + k;
                float4 v = make_float4(0.f, 0.f, 0.f, 0.f);
                if (kg < NQ) v = *(const float4*)(Vp + ((size_t)bh * NQ + kg) * HD + vd4);
                *(float4*)&Vt[k * 36 + vd4] = v;
            }
            __syncthreads();
            int klim = (kt2 == 5) ? 24 : 64;   // S row only valid to col 343; >=336 are exp(0-m) but V=0 anyway up to 336..343; beyond 344 unsafe
            for (int kk = 0; kk < klim; ++kk) {
                float p = S[q * ST + kt2 * 64 + kk];
                float4 v = *(const float4*)&Vt[kk * 36 + d4];
                o.x = fmaf(p, v.x, o.x); o.y = fmaf(p, v.y, o.y);
                o.z = fmaf(p, v.z, o.z); o.w = fmaf(p, v.w, o.w);
            }
        }
        int qg = q0 + q;
        if (qg < NQ) {
            int b = bh >> 3, h = bh & 7;
            *(float4*)(attn_o + ((size_t)(b * NQ + qg)) * DD + h * HD + d4) = o;
        }
    }
}

// ---------------- fused GEMM (4 rows/block, N=256,K=256) + residual + LayerNorm on x ------
__global__ __launch_bounds__(256) void gemm4_res_ln(const float* __restrict__ A,
                                                    const float* __restrict__ Wt,
                                                    const float* __restrict__ bias,
                                                    const float* __restrict__ gam,
                                                    const float* __restrict__ bet,
                                                    float* __restrict__ x) {
    __shared__ float sA[4 * DD];
    __shared__ float redS[4][4], redS2[4][4];
    __shared__ float mu[4], ri[4];
    int r0 = blockIdx.x * 4;
    int j = threadIdx.x;
    ((float4*)sA)[j] = ((const float4*)(A + (size_t)r0 * DD))[j];
    __syncthreads();
    float acc0 = bias[j], acc1 = acc0, acc2 = acc0, acc3 = acc0;
    const float* wp = Wt + (size_t)j * DD;
    for (int k = 0; k < DD; k += 4) {
        float4 w  = *(const float4*)(wp + k);
        float4 a0 = *(const float4*)(sA + 0 * DD + k);
        float4 a1 = *(const float4*)(sA + 1 * DD + k);
        float4 a2 = *(const float4*)(sA + 2 * DD + k);
        float4 a3 = *(const float4*)(sA + 3 * DD + k);
        acc0 = fmaf(a0.x, w.x, acc0); acc0 = fmaf(a0.y, w.y, acc0); acc0 = fmaf(a0.z, w.z, acc0); acc0 = fmaf(a0.w, w.w, acc0);
        acc1 = fmaf(a1.x, w.x, acc1); acc1 = fmaf(a1.y, w.y, acc1); acc1 = fmaf(a1.z, w.z, acc1); acc1 = fmaf(a1.w, w.w, acc1);
        acc2 = fmaf(a2.x, w.x, acc2); acc2 = fmaf(a2.y, w.y, acc2); acc2 = fmaf(a2.z, w.z, acc2); acc2 = fmaf(a2.w, w.w, acc2);
        acc3 = fmaf(a3.x, w.x, acc3); acc3 = fmaf(a3.y, w.y, acc3); acc3 = fmaf(a3.z, w.z, acc3); acc3 = fmaf(a3.w, w.w, acc3);
    }
    float val[4];
    val[0] = x[(size_t)(r0 + 0) * DD + j] + acc0;
    val[1] = x[(size_t)(r0 + 1) * DD + j] + acc1;
    val[2] = x[(size_t)(r0 + 2) * DD + j] + acc2;
    val[3] = x[(size_t)(r0 + 3) * DD + j] + acc3;
    float s[4], s2[4];
    #pragma unroll
    for (int r = 0; r < 4; ++r) { s[r] = val[r]; s2[r] = val[r] * val[r]; }
    #pragma unroll
    for (int o2 = 32; o2 > 0; o2 >>= 1) {
        #pragma unroll
        for (int r = 0; r < 4; ++r) {
            s[r]  += __shfl_xor(s[r],  o2);
            s2[r] += __shfl_xor(s2[r], o2);
        }
    }
    int wid = j >> 6, lane = j & 63;
    if (lane == 0) {
        #pragma unroll
        for (int r = 0; r < 4; ++r) { redS[r][wid] = s[r]; redS2[r][wid] = s2[r]; }
    }
    __syncthreads();
    if (j < 4) {
        int r = j;
        float ts  = redS[r][0]  + redS[r][1]  + redS[r][2]  + redS[r][3];
        float ts2 = redS2[r][0] + redS2[r][1] + redS2[r][2] + redS2[r][3];
        float mean = ts * (1.f / DD);
        float var = ts2 * (1.f / DD) - mean * mean;
        mu[r] = mean;
        ri[r] = rsqrtf(var + 1e-5f);
    }
    __syncthreads();
    float g = gam[j], be = bet[j];
    #pragma unroll
    for (int r = 0; r < 4; ++r)
        x[(size_t)(r0 + r) * DD + j] = (val[r] - mu[r]) * ri[r] * g + be;
}

// ---------------- bilinear sample helper ----------------
template <bool TRANSPOSED>
__device__ __forceinline__ float sample_level(const float* __restrict__ f, int bv, int Hh,
                                              float un, float vn, int dth) {
    int Ww = Hh;
    float xx = (un + 1.f) * Ww * 0.5f - 0.5f;
    float yy = (vn + 1.f) * Hh * 0.5f - 0.5f;
    float x0f = floorf(xx), y0f = floorf(yy);
    int ix0 = (int)x0f, iy0 = (int)y0f;
    float wx1 = xx - x0f, wx0 = 1.f - wx1;
    float wy1 = yy - y0f, wy0 = 1.f - wy1;
    float s = 0.f;
#define TAP(IX, IY, W)                                                           \
    {                                                                            \
        int ix = (IX), iy = (IY);                                                \
        if (ix >= 0 && ix < Ww && iy >= 0 && iy < Hh) {                          \
            float v;                                                             \
            if (TRANSPOSED)                                                      \
                v = f[((size_t)bv * Hh * Ww + (size_t)iy * Ww + ix) * DD + dth]; \
            else                                                                 \
                v = f[(((size_t)bv * DD + dth) * Hh + iy) * Ww + ix];            \
            s = fmaf((W), v, s);                                                 \
        }                                                                        \
    }
    TAP(ix0,     iy0,     wy0 * wx0)
    TAP(ix0 + 1, iy0,     wy0 * wx1)
    TAP(ix0,     iy0 + 1, wy1 * wx0)
    TAP(ix0 + 1, iy0 + 1, wy1 * wx1)
#undef TAP
    return s;
}

// ---------------- fused: project + sample + proj-GEMM + residual + LN, 4 rows/block -------
template <bool TRANSPOSED>
__global__ __launch_bounds__(256) void sample_proj_ln(const float* __restrict__ f0,
                                                      const float* __restrict__ f1,
                                                      const float* __restrict__ f2,
                                                      const float* __restrict__ refb,
                                                      const float* __restrict__ Rm,
                                                      const float* __restrict__ Tm,
                                                      const float* __restrict__ Km,
                                                      const float* __restrict__ Wproj,
                                                      const float* __restrict__ bproj,
                                                      const float* __restrict__ gam,
                                                      const float* __restrict__ bet,
                                                      float* __restrict__ x) {
    __shared__ float sF[4 * DD];
    __shared__ float sg[32][3];
    __shared__ float redS[4][4], redS2[4][4];
    __shared__ float mu[4], ri[4];
    int r0 = blockIdx.x * 4;
    int t = threadIdx.x;
    if (t < 32) {
        int rr = t >> 3, v = t & 7;
        int row = r0 + rr;
        int b = row / NQ;
        int bv = b * VV + v;
        const float* r = refb + (size_t)row * 3;
        const float* R = Rm + (size_t)bv * 9;
        const float* T = Tm + (size_t)bv * 3;
        const float* K = Km + (size_t)bv * 9;
        float p0 = R[0] * r[0] + R[1] * r[1] + R[2] * r[2] + T[0];
        float p1 = R[3] * r[0] + R[4] * r[1] + R[5] * r[2] + T[1];
        float p2 = R[6] * r[0] + R[7] * r[1] + R[8] * r[2] + T[2];
        float z = fmaxf(p2, 0.1f);
        float u  = p0 * K[0] / z + K[2];
        float vv = p1 * K[4] / z + K[5];
        float un = 2.f * u  / (float)(W_IMG - 1) - 1.f;
        float vn = 2.f * vv / (float)(H_IMG - 1) - 1.f;
        bool m = (un > -1.f) && (un < 1.f) && (vn > -1.f) && (vn < 1.f) && (p2 > 0.f);
        sg[t][0] = un; sg[t][1] = vn; sg[t][2] = m ? 1.f : 0.f;
    }
    __syncthreads();
    #pragma unroll
    for (int rr = 0; rr < 4; ++rr) {
        int row = r0 + rr;
        int b = row / NQ;
        float acc = 0.f, cnt = 0.f;
        for (int v = 0; v < VV; ++v) {
            float m = sg[rr * 8 + v][2];
            if (m == 0.f) continue;
            cnt += 1.f;
            float un = sg[rr * 8 + v][0], vn = sg[rr * 8 + v][1];
            int bv = b * VV + v;
            float ms = sample_level<TRANSPOSED>(f0, bv, 64, un, vn, t)
                     + sample_level<TRANSPOSED>(f1, bv, 32, un, vn, t)
                     + sample_level<TRANSPOSED>(f2, bv, 16, un, vn, t);
            acc += ms * (1.f / 3.f);
        }
        sF[rr * DD + t] = acc / fmaxf(cnt, 1.f);
    }
    __syncthreads();
    // proj GEMM: col t, 4 rows, K=256
    float acc0 = bproj[t], acc1 = acc0, acc2 = acc0, acc3 = acc0;
    const float* wp = Wproj + (size_t)t * DD;
    for (int k = 0; k < DD; k += 4) {
        float4 w  = *(const float4*)(wp + k);
        float4 a0 = *(const float4*)(sF + 0 * DD + k);
        float4 a1 = *(const float4*)(sF + 1 * DD + k);
        float4 a2 = *(const float4*)(sF + 2 * DD + k);
        float4 a3 = *(const float4*)(sF + 3 * DD + k);
        acc0 = fmaf(a0.x, w.x, acc0); acc0 = fmaf(a0.y, w.y, acc0); acc0 = fmaf(a0.z, w.z, acc0); acc0 = fmaf(a0.w, w.w, acc0);
        acc1 = fmaf(a1.x, w.x, acc1); acc1 = fmaf(a1.y, w.y, acc1); acc1 = fmaf(a1.z, w.z, acc1); acc1 = fmaf(a1.w, w.w, acc1);
        acc2 = fmaf(a2.x, w.x, acc2); acc2 = fmaf(a2.y, w.y, acc2); acc2 = fmaf(a2.z, w.z, acc2); acc2 = fmaf(a2.w, w.w, acc2);
        acc3 = fmaf(a3.x, w.x, acc3); acc3 = fmaf(a3.y, w.y, acc3); acc3 = fmaf(a3.z, w.z, acc3); acc3 = fmaf(a3.w, w.w, acc3);
    }
    float val[4];
    val[0] = x[(size_t)(r0 + 0) * DD + t] + acc0;
    val[1] = x[(size_t)(r0 + 1) * DD + t] + acc1;
    val[2] = x[(size_t)(r0 + 2) * DD + t] + acc2;
    val[3] = x[(size_t)(r0 + 3) * DD + t] + acc3;
    float s[4], s2[4];
    #pragma unroll
    for (int r = 0; r < 4; ++r) { s[r] = val[r]; s2[r] = val[r] * val[r]; }
    #pragma unroll
    for (int o2 = 32; o2 > 0; o2 >>= 1) {
        #pragma unroll
        for (int r = 0; r < 4; ++r) {
            s[r]  += __shfl_xor(s[r],  o2);
            s2[r] += __shfl_xor(s2[r], o2);
        }
    }
    int wid = t >> 6, lane = t & 63;
    if (lane == 0) {
        #pragma unroll
        for (int r = 0; r < 4; ++r) { redS[r][wid] = s[r]; redS2[r][wid] = s2[r]; }
    }
    __syncthreads();
    if (t < 4) {
        int r = t;
        float ts  = redS[r][0]  + redS[r][1]  + redS[r][2]  + redS[r][3];
        float ts2 = redS2[r][0] + redS2[r][1] + redS2[r][2] + redS2[r][3];
        float mean = ts * (1.f / DD);
        float var = ts2 * (1.f / DD) - mean * mean;
        mu[r] = mean;
        ri[r] = rsqrtf(var + 1e-5f);
    }
    __syncthreads();
    float g = gam[t], be = bet[t];
    #pragma unroll
    for (int r = 0; r < 4; ++r)
        x[(size_t)(r0 + r) * DD + t] = (val[r] - mu[r]) * ri[r] * g + be;
}

// ---------------- fused FFN (1024) + LN2 + xq + pose MLP + heads, 4 rows/block ------------
__global__ __launch_bounds__(256) void ffn_pose(float* __restrict__ x,
                                                float* __restrict__ xq,
                                                const float* __restrict__ W1,
                                                const float* __restrict__ b1,
                                                const float* __restrict__ W2,
                                                const float* __restrict__ b2,
                                                const float* __restrict__ g2,
                                                const float* __restrict__ be2,
                                                const float* __restrict__ qp,
                                                const float* __restrict__ pW0,
                                                const float* __restrict__ pb0,
                                                const float* __restrict__ pW1,
                                                const float* __restrict__ pb1,
                                                const float* __restrict__ pW2,
                                                const float* __restrict__ pb2,
                                                const float* __restrict__ cW,
                                                const float* __restrict__ cb,
                                                float* __restrict__ refb,
                                                float* __restrict__ outp) {
    __shared__ float sX[4 * DD];
    __shared__ float sH[4 * FF];
    __shared__ float redS[4][4], redS2[4][4];
    __shared__ float mu[4], ri[4];
    __shared__ float pred[4][4][4];
    int r0 = blockIdx.x * 4;
    int j = threadIdx.x;
    ((float4*)sX)[j] = ((const float4*)(x + (size_t)r0 * DD))[j];
    __syncthreads();
    // ---- ffn1: cols j + p*256, 4 rows, K=256 (16 accumulators, W streamed 4-way) ----
    {
        float acc[4][4];
        #pragma unroll
        for (int p = 0; p < 4; ++p) {
            float b = b1[j + p * 256];
            acc[p][0] = b; acc[p][1] = b; acc[p][2] = b; acc[p][3] = b;
        }
        const float* wp0 = W1 + (size_t)(j + 0)       * DD;
        const float* wp1 = W1 + (size_t)(j + 256)     * DD;
        const float* wp2 = W1 + (size_t)(j + 512)     * DD;
        const float* wp3 = W1 + (size_t)(j + 768)     * DD;
        for (int k = 0; k < DD; k += 4) {
            float4 a0 = *(const float4*)(sX + 0 * DD + k);
            float4 a1 = *(const float4*)(sX + 1 * DD + k);
            float4 a2 = *(const float4*)(sX + 2 * DD + k);
            float4 a3 = *(const float4*)(sX + 3 * DD + k);
            float4 w;
            w = *(const float4*)(wp0 + k);
            acc[0][0] = fmaf(a0.x, w.x, acc[0][0]); acc[0][0] = fmaf(a0.y, w.y, acc[0][0]); acc[0][0] = fmaf(a0.z, w.z, acc[0][0]); acc[0][0] = fmaf(a0.w, w.w, acc[0][0]);
            acc[0][1] = fmaf(a1.x, w.x, acc[0][1]); acc[0][1] = fmaf(a1.y, w.y, acc[0][1]); acc[0][1] = fmaf(a1.z, w.z, acc[0][1]); acc[0][1] = fmaf(a1.w, w.w, acc[0][1]);
            acc[0][2] = fmaf(a2.x, w.x, acc[0][2]); acc[0][2] = fmaf(a2.y, w.y, acc[0][2]); acc[0][2] = fmaf(a2.z, w.z, acc[0][2]); acc[0][2] = fmaf(a2.w, w.w, acc[0][2]);
            acc[0][3] = fmaf(a3.x, w.x, acc[0][3]); acc[0][3] = fmaf(a3.y, w.y, acc[0][3]); acc[0][3] = fmaf(a3.z, w.z, acc[0][3]); acc[0][3] = fmaf(a3.w, w.w, acc[0][3]);
            w = *(const float4*)(wp1 + k);
            acc[1][0] = fmaf(a0.x, w.x, acc[1][0]); acc[1][0] = fmaf(a0.y, w.y, acc[1][0]); acc[1][0] = fmaf(a0.z, w.z, acc[1][0]); acc[1][0] = fmaf(a0.w, w.w, acc[1][0]);
            acc[1][1] = fmaf(a1.x, w.x, acc[1][1]); acc[1][1] = fmaf(a1.y, w.y, acc[1][1]); acc[1][1] = fmaf(a1.z, w.z, acc[1][1]); acc[1][1] = fmaf(a1.w, w.w, acc[1][1]);
            acc[1][2] = fmaf(a2.x, w.x, acc[1][2]); acc[1][2] = fmaf(a2.y, w.y, acc[1][2]); acc[1][2] = fmaf(a2.z, w.z, acc[1][2]); acc[1][2] = fmaf(a2.w, w.w, acc[1][2]);
            acc[1][3] = fmaf(a3.x, w.x, acc[1][3]); acc[1][3] = fmaf(a3.y, w.y, acc[1][3]); acc[1][3] = fmaf(a3.z, w.z, acc[1][3]); acc[1][3] = fmaf(a3.w, w.w, acc[1][3]);
            w = *(const float4*)(wp2 + k);
            acc[2][0] = fmaf(a0.x, w.x, acc[2][0]); acc[2][0] = fmaf(a0.y, w.y, acc[2][0]); acc[2][0] = fmaf(a0.z, w.z, acc[2][0]); acc[2][0] = fmaf(a0.w, w.w, acc[2][0]);
            acc[2][1] = fmaf(a1.x, w.x, acc[2][1]); acc[2][1] = fmaf(a1.y, w.y, acc[2][1]); acc[2][1] = fmaf(a1.z, w.z, acc[2][1]); acc[2][1] = fmaf(a1.w, w.w, acc[2][1]);
            acc[2][2] = fmaf(a2.x, w.x, acc[2][2]); acc[2][2] = fmaf(a2.y, w.y, acc[2][2]); acc[2][2] = fmaf(a2.z, w.z, acc[2][2]); acc[2][2] = fmaf(a2.w, w.w, acc[2][2]);
            acc[2][3] = fmaf(a3.x, w.x, acc[2][3]); acc[2][3] = fmaf(a3.y, w.y, acc[2][3]); acc[2][3] = fmaf(a3.z, w.z, acc[2][3]); acc[2][3] = fmaf(a3.w, w.w, acc[2][3]);
            w = *(const float4*)(wp3 + k);
            acc[3][0] = fmaf(a0.x, w.x, acc[3][0]); acc[3][0] = fmaf(a0.y, w.y, acc[3][0]); acc[3][0] = fmaf(a0.z, w.z, acc[3][0]); acc[3][0] = fmaf(a0.w, w.w, acc[3][0]);
            acc[3][1] = fmaf(a1.x, w.x, acc[3][1]); acc[3][1] = fmaf(a1.y, w.y, acc[3][1]); acc[3][1] = fmaf(a1.z, w.z, acc[3][1]); acc[3][1] = fmaf(a1.w, w.w, acc[3][1]);
            acc[3][2] = fmaf(a2.x, w.x, acc[3][2]); acc[3][2] = fmaf(a2.y, w.y, acc[3][2]); acc[3][2] = fmaf(a2.z, w.z, acc[3][2]); acc[3][2] = fmaf(a2.w, w.w, acc[3][2]);
            acc[3][3] = fmaf(a3.x, w.x, acc[3][3]); acc[3][3] = fmaf(a3.y, w.y, acc[3][3]); acc[3][3] = fmaf(a3.z, w.z, acc[3][3]); acc[3][3] = fmaf(a3.w, w.w, acc[3][3]);
        }
        #pragma unroll
        for (int p = 0; p < 4; ++p) {
            int col = j + p * 256;
            sH[0 * FF + col] = fmaxf(acc[p][0], 0.f);
            sH[1 * FF + col] = fmaxf(acc[p][1], 0.f);
            sH[2 * FF + col] = fmaxf(acc[p][2], 0.f);
            sH[3 * FF + col] = fmaxf(acc[p][3], 0.f);
        }
    }
    __syncthreads();
    // ---- ffn2: col j, 4 rows, K=1024 ----
    float val[4];
    {
        float a0 = b2[j], a1 = a0, a2 = a0, a3 = a0;
        const float* wp = W2 + (size_t)j * FF;
        for (int k = 0; k < FF; k += 4) {
            float4 w  = *(const float4*)(wp + k);
            float4 h0 = *(const float4*)(sH + 0 * FF + k);
            float4 h1 = *(const float4*)(sH + 1 * FF + k);
            float4 h2 = *(const float4*)(sH + 2 * FF + k);
            float4 h3 = *(const float4*)(sH + 3 * FF + k);
            a0 = fmaf(h0.x, w.x, a0); a0 = fmaf(h0.y, w.y, a0); a0 = fmaf(h0.z, w.z, a0); a0 = fmaf(h0.w, w.w, a0);
            a1 = fmaf(h1.x, w.x, a1); a1 = fmaf(h1.y, w.y, a1); a1 = fmaf(h1.z, w.z, a1); a1 = fmaf(h1.w, w.w, a1);
            a2 = fmaf(h2.x, w.x, a2); a2 = fmaf(h2.y, w.y, a2); a2 = fmaf(h2.z, w.z, a2); a2 = fmaf(h2.w, w.w, a2);
            a3 = fmaf(h3.x, w.x, a3); a3 = fmaf(h3.y, w.y, a3); a3 = fmaf(h3.z, w.z, a3); a3 = fmaf(h3.w, w.w, a3);
        }
        val[0] = sX[0 * DD + j] + a0;
        val[1] = sX[1 * DD + j] + a1;
        val[2] = sX[2 * DD + j] + a2;
        val[3] = sX[3 * DD + j] + a3;
    }
    // ---- LN2 ----
    {
        float s[4], s2[4];
        #pragma unroll
        for (int r = 0; r < 4; ++r) { s[r] = val[r]; s2[r] = val[r] * val[r]; }
        #pragma unroll
        for (int o2 = 32; o2 > 0; o2 >>= 1) {
            #pragma unroll
            for (int r = 0; r < 4; ++r) {
                s[r]  += __shfl_xor(s[r],  o2);
                s2[r] += __shfl_xor(s2[r], o2);
            }
        }
        int wid = j >> 6, lane = j & 63;
        if (lane == 0) {
            #pragma unroll
            for (int r = 0; r < 4; ++r) { redS[r][wid] = s[r]; redS2[r][wid] = s2[r]; }
        }
        __syncthreads();
        if (j < 4) {
            int r = j;
            float ts  = redS[r][0]  + redS[r][1]  + redS[r][2]  + redS[r][3];
            float ts2 = redS2[r][0] + redS2[r][1] + redS2[r][2] + redS2[r][3];
            float mean = ts * (1.f / DD);
            float var = ts2 * (1.f / DD) - mean * mean;
            mu[r] = mean;
            ri[r] = rsqrtf(var + 1e-5f);
        }
        __syncthreads();
    }
    float nx[4];
    {
        float g = g2[j], be = be2[j];
        #pragma unroll
        for (int r = 0; r < 4; ++r) {
            nx[r] = (val[r] - mu[r]) * ri[r] * g + be;
            x[(size_t)(r0 + r) * DD + j]  = nx[r];
            xq[(size_t)(r0 + r) * DD + j] = nx[r] + qp[(size_t)(r0 + r) * DD + j];
        }
    }
    __syncthreads();
    #pragma unroll
    for (int r = 0; r < 4; ++r) sX[r * DD + j] = nx[r];
    __syncthreads();
    // ---- pose0: h1 = relu(nx @ pW0^T + pb0), into sH[0..4*DD) ----
    {
        float a0 = pb0[j], a1 = a0, a2 = a0, a3 = a0;
        const float* wp = pW0 + (size_t)j * DD;
        for (int k = 0; k < DD; k += 4) {
            float4 w  = *(const float4*)(wp + k);
            float4 x0 = *(const float4*)(sX + 0 * DD + k);
            float4 x1 = *(const float4*)(sX + 1 * DD + k);
            float4 x2 = *(const float4*)(sX + 2 * DD + k);
            float4 x3 = *(const float4*)(sX + 3 * DD + k);
            a0 = fmaf(x0.x, w.x, a0); a0 = fmaf(x0.y, w.y, a0); a0 = fmaf(x0.z, w.z, a0); a0 = fmaf(x0.w, w.w, a0);
            a1 = fmaf(x1.x, w.x, a1); a1 = fmaf(x1.y, w.y, a1); a1 = fmaf(x1.z, w.z, a1); a1 = fmaf(x1.w, w.w, a1);
            a2 = fmaf(x2.x, w.x, a2); a2 = fmaf(x2.y, w.y, a2); a2 = fmaf(x2.z, w.z, a2); a2 = fmaf(x2.w, w.w, a2);
            a3 = fmaf(x3.x, w.x, a3); a3 = fmaf(x3.y, w.y, a3); a3 = fmaf(x3.z, w.z, a3); a3 = fmaf(x3.w, w.w, a3);
        }
        sH[0 * DD + j] = fmaxf(a0, 0.f);
        sH[1 * DD + j] = fmaxf(a1, 0.f);
        sH[2 * DD + j] = fmaxf(a2, 0.f);
        sH[3 * DD + j] = fmaxf(a3, 0.f);
    }
    __syncthreads();
    // ---- pose1: h2 = relu(h1 @ pW1^T + pb1), kept in regs ----
    float h[4];
    {
        float a0 = pb1[j], a1 = a0, a2 = a0, a3 = a0;
        const float* wp = pW1 + (size_t)j * DD;
        for (int k = 0; k < DD; k += 4) {
            float4 w  = *(const float4*)(wp + k);
            float4 x0 = *(const float4*)(sH + 0 * DD + k);
            float4 x1 = *(const float4*)(sH + 1 * DD + k);
            float4 x2 = *(const float4*)(sH + 2 * DD + k);
            float4 x3 = *(const float4*)(sH + 3 * DD + k);
            a0 = fmaf(x0.x, w.x, a0); a0 = fmaf(x0.y, w.y, a0); a0 = fmaf(x0.z, w.z, a0); a0 = fmaf(x0.w, w.w, a0);
            a1 = fmaf(x1.x, w.x, a1); a1 = fmaf(x1.y, w.y, a1); a1 = fmaf(x1.z, w.z, a1); a1 = fmaf(x1.w, w.w, a1);
            a2 = fmaf(x2.x, w.x, a2); a2 = fmaf(x2.y, w.y, a2); a2 = fmaf(x2.z, w.z, a2); a2 = fmaf(x2.w, w.w, a2);
            a3 = fmaf(x3.x, w.x, a3); a3 = fmaf(x3.y, w.y, a3); a3 = fmaf(x3.z, w.z, a3); a3 = fmaf(x3.w, w.w, a3);
        }
        h[0] = fmaxf(a0, 0.f); h[1] = fmaxf(a1, 0.f); h[2] = fmaxf(a2, 0.f); h[3] = fmaxf(a3, 0.f);
    }
    // ---- heads: pose delta (3) from h2, cls (1) from nx ----
    {
        float w2a = pW2[j], w2b = pW2[DD + j], w2c = pW2[2 * DD + j], cw = cW[j];
        float v[4][4];
        #pragma unroll
        for (int r = 0; r < 4; ++r) {
            v[r][0] = h[r] * w2a;
            v[r][1] = h[r] * w2b;
            v[r][2] = h[r] * w2c;
            v[r][3] = sX[r * DD + j] * cw;
        }
        #pragma unroll
        for (int o2 = 32; o2 > 0; o2 >>= 1) {
            #pragma unroll
            for (int r = 0; r < 4; ++r) {
                #pragma unroll
                for (int c = 0; c < 4; ++c) v[r][c] += __shfl_xor(v[r][c], o2);
            }
        }
        int wid = j >> 6, lane = j & 63;
        if (lane == 0) {
            #pragma unroll
            for (int r = 0; r < 4; ++r)
                #pragma unroll
                for (int c = 0; c < 4; ++c) pred[r][c][wid] = v[r][c];
        }
        __syncthreads();
        if (j < 4) {
            int r = j;
            float d0 = pred[r][0][0] + pred[r][0][1] + pred[r][0][2] + pred[r][0][3] + pb2[0];
            float d1 = pred[r][1][0] + pred[r][1][1] + pred[r][1][2] + pred[r][1][3] + pb2[1];
            float d2 = pred[r][2][0] + pred[r][2][1] + pred[r][2][2] + pred[r][2][3] + pb2[2];
            float cl = pred[r][3][0] + pred[r][3][1] + pred[r][3][2] + pred[r][3][3] + cb[0];
            int row = r0 + r;
            float rx = refb[(size_t)row * 3 + 0] + d0;
            float ry = refb[(size_t)row * 3 + 1] + d1;
            float rz = refb[(size_t)row * 3 + 2] + d2;
            refb[(size_t)row * 3 + 0] = rx;
            refb[(size_t)row * 3 + 1] = ry;
            refb[(size_t)row * 3 + 2] = rz;
            outp[(size_t)row * 4 + 0] = cl;
            outp[(size_t)row * 4 + 1] = rx;
            outp[(size_t)row * 4 + 2] = ry;
            outp[(size_t)row * 4 + 3] = rz;
        }
    }
}

extern "C" void kernel_launch(void* const* d_in, const int* in_sizes, int n_in,
                              void* d_out, int out_size, void* d_ws, size_t ws_size,
                              hipStream_t stream) {
    const float* tgt       = (const float*)d_in[0];
    const float* query_pos = (const float*)d_in[1];
    const float* refpts    = (const float*)d_in[2];
    const float* feat0     = (const float*)d_in[3];
    const float* feat1     = (const float*)d_in[4];
    const float* feat2     = (const float*)d_in[5];
    const float* camR      = (const float*)d_in[6];
    const float* camT      = (const float*)d_in[7];
    const float* camK      = (const float*)d_in[8];
    const float* Wqkv      = (const float*)d_in[9];
    const float* bqkv      = (const float*)d_in[10];
    const float* Wo        = (const float*)d_in[11];
    const float* bo        = (const float*)d_in[12];
    const float* ln1_g     = (const float*)d_in[13];
    const float* ln1_b     = (const float*)d_in[14];
    const float* Wproj     = (const float*)d_in[15];
    const float* bproj     = (const float*)d_in[16];
    const float* pn_g      = (const float*)d_in[17];
    const float* pn_b      = (const float*)d_in[18];
    const float* W1        = (const float*)d_in[19];
    const float* b1        = (const float*)d_in[20];
    const float* W2        = (const float*)d_in[21];
    const float* b2        = (const float*)d_in[22];
    const float* ln2_g     = (const float*)d_in[23];
    const float* ln2_b     = (const float*)d_in[24];
    const float* pose_W0   = (const float*)d_in[25];
    const float* pose_b0   = (const float*)d_in[26];
    const float* pose_W1   = (const float*)d_in[27];
    const float* pose_b1   = (const float*)d_in[28];
    const float* pose_W2   = (const float*)d_in[29];
    const float* pose_b2   = (const float*)d_in[30];
    const float* cls_W     = (const float*)d_in[31];
    const float* cls_b     = (const float*)d_in[32];
    float* out = (float*)d_out;

    float* w = (float*)d_ws;
    size_t off = 0;
    auto alloc = [&](size_t n) { float* p = w + off; off += n; return p; };
    float* x      = alloc((size_t)BQ * DD);
    float* xq     = alloc((size_t)BQ * DD);
    float* Qp     = alloc((size_t)BB * HEADS * NQ * HD);
    float* Kp     = alloc((size_t)BB * HEADS * NQ * HD);
    float* Vp     = alloc((size_t)BB * HEADS * NQ * HD);
    float* attn_o = alloc((size_t)BQ * DD);
    float* refb   = alloc((size_t)BQ * 3 + 64);
    size_t base_floats = off;
    size_t featT_floats = (size_t)BB * VV * DD * (64 * 64 + 32 * 32 + 16 * 16);
    bool useT = ws_size >= (base_floats + featT_floats) * sizeof(float);
    float *fT0 = nullptr, *fT1 = nullptr, *fT2 = nullptr;
    if (useT) {
        fT0 = alloc((size_t)BB * VV * 64 * 64 * DD);
        fT1 = alloc((size_t)BB * VV * 32 * 32 * DD);
        fT2 = alloc((size_t)BB * VV * 16 * 16 * DD);
    }

    init_k<<<BQ * DD / 4 / 256, 256, 0, stream>>>(tgt, query_pos, refpts, x, xq, refb);
    if (useT)
        transpose_all<<<5376, 256, 0, stream>>>(feat0, feat1, feat2, fT0, fT1, fT2);

    for (int l = 0; l < NL; ++l) {
        qkv_tile<<<dim3(21, 12), 256, 0, stream>>>(
            xq, x, Wqkv + (size_t)l * 3 * DD * DD, bqkv + (size_t)l * 3 * DD, Qp, Kp, Vp);
        attn_fused<<<176, 256, 0, stream>>>(Qp, Kp, Vp, attn_o);
        gemm4_res_ln<<<BQ / 4, 256, 0, stream>>>(
            attn_o, Wo + (size_t)l * DD * DD, bo + (size_t)l * DD,
            ln1_g + (size_t)l * DD, ln1_b + (size_t)l * DD, x);
        if (useT)
            sample_proj_ln<true><<<BQ / 4, 256, 0, stream>>>(
                fT0, fT1, fT2, refb, camR, camT, camK,
                Wproj + (size_t)l * DD * DD, bproj + (size_t)l * DD,
                pn_g + (size_t)l * DD, pn_b + (size_t)l * DD, x);
        else
            sample_proj_ln<false><<<BQ / 4, 256, 0, stream>>>(
                feat0, feat1, feat2, refb, camR, camT, camK,
                Wproj + (size_t)l * DD * DD, bproj + (size_t)l * DD,
                pn_g + (size_t)l * DD, pn_b + (size_t)l * DD, x);
        ffn_pose<<<BQ / 4, 256, 0, stream>>>(
            x, xq,
            W1 + (size_t)l * FF * DD, b1 + (size_t)l * FF,
            W2 + (size_t)l * DD * FF, b2 + (size_t)l * DD,
            ln2_g + (size_t)l * DD, ln2_b + (size_t)l * DD, query_pos,
            pose_W0, pose_b0, pose_W1, pose_b1, pose_W2, pose_b2, cls_W, cls_b,
            refb, out + (size_t)l * BQ * 4);
    }
}

// Round 7
// 1705.888 us; speedup vs baseline: 3.9269x; 1.5392x over previous
//
#include <hip/hip_runtime.h>
#include <math.h>

#define BB 2
#define VV 8
#define NQ 336
#define DD 256
#define HEADS 8
#define HD 32
#define FF 1024
#define NL 6
#define BQ (BB*NQ)
#define W_IMG 512
#define H_IMG 512
#define SP 384
#define MROWS BQ

// ---------------- merged LDS-tiled transpose: (BV,D,H,W) -> (BV,H,W,D) ----------------
__global__ __launch_bounds__(256) void transpose_all(const float* __restrict__ f0,
                                                     const float* __restrict__ f1,
                                                     const float* __restrict__ f2,
                                                     float* __restrict__ o0,
                                                     float* __restrict__ o1,
                                                     float* __restrict__ o2) {
    int b = blockIdx.x;
    const float* src; float* dst; int HW, ptiles;
    if (b < 4096)      { src = f0; dst = o0; HW = 4096; ptiles = 64; }
    else if (b < 5120) { b -= 4096; src = f1; dst = o1; HW = 1024; ptiles = 16; }
    else               { b -= 5120; src = f2; dst = o2; HW = 256;  ptiles = 4;  }
    int cg = b & 3;
    int pt = (b >> 2) % ptiles;
    int bv = (b >> 2) / ptiles;
    int d0 = cg * 64, p0 = pt * 64;
    __shared__ float tile[64][65];
    int tid = threadIdx.x;
    int t4 = tid >> 4, t15 = tid & 15;
    #pragma unroll
    for (int pass = 0; pass < 4; ++pass) {
        int d = pass * 16 + t4;
        int p = t15 * 4;
        float4 v = *(const float4*)(src + ((size_t)(bv * DD + d0 + d)) * HW + p0 + p);
        tile[d][p] = v.x; tile[d][p + 1] = v.y; tile[d][p + 2] = v.z; tile[d][p + 3] = v.w;
    }
    __syncthreads();
    #pragma unroll
    for (int pass = 0; pass < 4; ++pass) {
        int p = pass * 16 + t4;
        int d = t15 * 4;
        float4 v = make_float4(tile[d][p], tile[d + 1][p], tile[d + 2][p], tile[d + 3][p]);
        *(float4*)(dst + ((size_t)bv * HW + p0 + p) * DD + d0 + d) = v;
    }
}

// ---------------- init ----------------
__global__ __launch_bounds__(256) void init_k(const float* __restrict__ tgt,
                                              const float* __restrict__ qp,
                                              const float* __restrict__ refpts,
                                              float* __restrict__ x,
                                              float* __restrict__ xq,
                                              float* __restrict__ refb) {
    int i = blockIdx.x * 256 + threadIdx.x;
    float4 tv = ((const float4*)tgt)[i];
    float4 qv = ((const float4*)qp)[i];
    ((float4*)x)[i] = tv;
    ((float4*)xq)[i] = make_float4(tv.x + qv.x, tv.y + qv.y, tv.z + qv.z, tv.w + qv.w);
    if (i < BQ * 3) refb[i] = refpts[i];
}

// ---------------- QKV tiled GEMM, head-packed output. grid (21, 12) ----------------
__global__ __launch_bounds__(256) void qkv_tile(const float* __restrict__ Aq,
                                                const float* __restrict__ Ax,
                                                const float* __restrict__ W,
                                                const float* __restrict__ bias,
                                                float* __restrict__ Qp,
                                                float* __restrict__ Kp,
                                                float* __restrict__ Vp) {
    __shared__ float At[32][34];
    __shared__ float Wt[32][68];
    int t = threadIdx.x;
    int m0 = blockIdx.x * 32;
    int n0 = blockIdx.y * 64;
    const float* A = (blockIdx.y < 8) ? Aq : Ax;
    int tx = t & 15, ty = t >> 4;
    int nc = n0 + tx * 4;
    float acc0[4], acc1[4];
    {
        float4 bv = *(const float4*)(bias + nc);
        acc0[0] = bv.x; acc0[1] = bv.y; acc0[2] = bv.z; acc0[3] = bv.w;
        acc1[0] = bv.x; acc1[1] = bv.y; acc1[2] = bv.z; acc1[3] = bv.w;
    }
    int am = t >> 3, ak4 = (t & 7) * 4;
    for (int kt = 0; kt < 8; ++kt) {
        int kk = kt * 32;
        __syncthreads();
        {
            float4 v = *(const float4*)(A + (size_t)(m0 + am) * DD + kk + ak4);
            At[ak4 + 0][am] = v.x; At[ak4 + 1][am] = v.y;
            At[ak4 + 2][am] = v.z; At[ak4 + 3][am] = v.w;
        }
        #pragma unroll
        for (int s = 0; s < 2; ++s) {
            int idx = t + s * 256;
            int wn = idx >> 3, wk4 = (idx & 7) * 4;
            float4 v = *(const float4*)(W + (size_t)(n0 + wn) * DD + kk + wk4);
            Wt[wk4 + 0][wn] = v.x; Wt[wk4 + 1][wn] = v.y;
            Wt[wk4 + 2][wn] = v.z; Wt[wk4 + 3][wn] = v.w;
        }
        __syncthreads();
        #pragma unroll
        for (int k = 0; k < 32; ++k) {
            float2 av = *(const float2*)&At[k][ty * 2];
            float4 wv = *(const float4*)&Wt[k][tx * 4];
            acc0[0] = fmaf(av.x, wv.x, acc0[0]); acc0[1] = fmaf(av.x, wv.y, acc0[1]);
            acc0[2] = fmaf(av.x, wv.z, acc0[2]); acc0[3] = fmaf(av.x, wv.w, acc0[3]);
            acc1[0] = fmaf(av.y, wv.x, acc1[0]); acc1[1] = fmaf(av.y, wv.y, acc1[1]);
            acc1[2] = fmaf(av.y, wv.z, acc1[2]); acc1[3] = fmaf(av.y, wv.w, acc1[3]);
        }
    }
    int mr = m0 + ty * 2;
    int kind = nc >> 8;
    float* base = kind == 0 ? Qp : (kind == 1 ? Kp : Vp);
    int h = (nc >> 5) & 7, d4 = nc & 31;
    #pragma unroll
    for (int i = 0; i < 2; ++i) {
        int m = mr + i;
        int b = m / NQ, q = m - b * NQ;
        float* p = base + ((size_t)((b << 3) + h) * NQ + q) * HD + d4;
        float* src = i == 0 ? acc0 : acc1;
        *(float4*)p = make_float4(src[0], src[1], src[2], src[3]);
    }
}

// ---------------- attention scores (scaled). grid (16, 6) ----------------
__global__ __launch_bounds__(256) void attn_scores(const float* __restrict__ Qp,
                                                   const float* __restrict__ Kp,
                                                   float* __restrict__ S) {
    int bh = blockIdx.x, qt = blockIdx.y;
    __shared__ float QT[32][68];
    __shared__ float KT[32][68];
    int t = threadIdx.x;
    const float scale = 0.17677669529663687f;
    const float* Qb = Qp + (size_t)bh * NQ * HD;
    const float* Kb = Kp + (size_t)bh * NQ * HD;
    #pragma unroll
    for (int s = 0; s < 2; ++s) {
        int idx = t + s * 256;
        int ql = idx >> 3, d4 = (idx & 7) * 4;
        int qg = qt * 64 + ql;
        float4 v = (qg < NQ) ? *(const float4*)(Qb + (size_t)qg * HD + d4)
                             : make_float4(0.f, 0.f, 0.f, 0.f);
        QT[d4 + 0][ql] = v.x * scale; QT[d4 + 1][ql] = v.y * scale;
        QT[d4 + 2][ql] = v.z * scale; QT[d4 + 3][ql] = v.w * scale;
    }
    int tx = t & 15, ty = t >> 4;
    for (int kt = 0; kt < 6; ++kt) {
        __syncthreads();
        #pragma unroll
        for (int s = 0; s < 2; ++s) {
            int idx = t + s * 256;
            int kl = idx >> 3, d4 = (idx & 7) * 4;
            int kg = kt * 64 + kl;
            float4 v = (kg < NQ) ? *(const float4*)(Kb + (size_t)kg * HD + d4)
                                 : make_float4(0.f, 0.f, 0.f, 0.f);
            KT[d4 + 0][kl] = v.x; KT[d4 + 1][kl] = v.y;
            KT[d4 + 2][kl] = v.z; KT[d4 + 3][kl] = v.w;
        }
        __syncthreads();
        float a0[4] = {0, 0, 0, 0}, a1[4] = {0, 0, 0, 0}, a2[4] = {0, 0, 0, 0}, a3[4] = {0, 0, 0, 0};
        #pragma unroll
        for (int k = 0; k < 32; ++k) {
            float4 qv = *(const float4*)&QT[k][ty * 4];
            float4 kv = *(const float4*)&KT[k][tx * 4];
            a0[0] = fmaf(qv.x, kv.x, a0[0]); a0[1] = fmaf(qv.x, kv.y, a0[1]);
            a0[2] = fmaf(qv.x, kv.z, a0[2]); a0[3] = fmaf(qv.x, kv.w, a0[3]);
            a1[0] = fmaf(qv.y, kv.x, a1[0]); a1[1] = fmaf(qv.y, kv.y, a1[1]);
            a1[2] = fmaf(qv.y, kv.z, a1[2]); a1[3] = fmaf(qv.y, kv.w, a1[3]);
            a2[0] = fmaf(qv.z, kv.x, a2[0]); a2[1] = fmaf(qv.z, kv.y, a2[1]);
            a2[2] = fmaf(qv.z, kv.z, a2[2]); a2[3] = fmaf(qv.z, kv.w, a2[3]);
            a3[0] = fmaf(qv.w, kv.x, a3[0]); a3[1] = fmaf(qv.w, kv.y, a3[1]);
            a3[2] = fmaf(qv.w, kv.z, a3[2]); a3[3] = fmaf(qv.w, kv.w, a3[3]);
        }
        int qg0 = qt * 64 + ty * 4;
        int kg0 = kt * 64 + tx * 4;
        float* Sb = S + ((size_t)bh * SP + qg0) * SP + kg0;
        *(float4*)(Sb + 0 * SP) = make_float4(a0[0], a0[1], a0[2], a0[3]);
        *(float4*)(Sb + 1 * SP) = make_float4(a1[0], a1[1], a1[2], a1[3]);
        *(float4*)(Sb + 2 * SP) = make_float4(a2[0], a2[1], a2[2], a2[3]);
        *(float4*)(Sb + 3 * SP) = make_float4(a3[0], a3[1], a3[2], a3[3]);
    }
}

// ---------------- PV with fused softmax. grid (16, 6) ----------------
// pass A: per-row max/sum over valid 336 cols (4 threads/row); pass B: PV with
// p = exp(s-m)*inv applied at Pt staging. V pad rows are 0 so pad cols are harmless.
__global__ __launch_bounds__(256) void attn_pv_sm(const float* __restrict__ S,
                                                  const float* __restrict__ Vp,
                                                  float* __restrict__ O) {
    int bh = blockIdx.x, qt = blockIdx.y;
    int b = bh >> 3, h = bh & 7;
    __shared__ float Pt[64][65];
    __shared__ float Vt[64][32];
    __shared__ float smi[64][2];
    int t = threadIdx.x;
    {   // softmax stats
        int r = t >> 2, cg = t & 3;
        const float* row = S + ((size_t)bh * SP + qt * 64 + r) * SP;
        float m = -1e30f;
        for (int i = 0; i < 84; ++i) m = fmaxf(m, row[cg + i * 4]);
        m = fmaxf(m, __shfl_xor(m, 1));
        m = fmaxf(m, __shfl_xor(m, 2));
        float ssum = 0.f;
        for (int i = 0; i < 84; ++i) ssum += expf(row[cg + i * 4] - m);
        ssum += __shfl_xor(ssum, 1);
        ssum += __shfl_xor(ssum, 2);
        if (cg == 0) { smi[r][0] = m; smi[r][1] = 1.f / ssum; }
    }
    __syncthreads();
    int tx = t & 7, ty = t >> 3;
    int d0 = tx * 4, q0 = ty * 2;
    float acc0[4] = {0, 0, 0, 0}, acc1[4] = {0, 0, 0, 0};
    for (int kt = 0; kt < 6; ++kt) {
        __syncthreads();
        #pragma unroll
        for (int s = 0; s < 4; ++s) {
            int idx = t + s * 256;
            int ql = idx >> 4, kk4 = (idx & 15) * 4;
            float4 v = *(const float4*)(S + ((size_t)bh * SP + qt * 64 + ql) * SP + kt * 64 + kk4);
            float m = smi[ql][0], inv = smi[ql][1];
            Pt[ql][kk4 + 0] = expf(v.x - m) * inv;
            Pt[ql][kk4 + 1] = expf(v.y - m) * inv;
            Pt[ql][kk4 + 2] = expf(v.z - m) * inv;
            Pt[ql][kk4 + 3] = expf(v.w - m) * inv;
        }
        #pragma unroll
        for (int s = 0; s < 2; ++s) {
            int idx = t + s * 256;
            int kl = idx >> 3, d4 = (idx & 7) * 4;
            int kg = kt * 64 + kl;
            float4 v = (kg < NQ) ? *(const float4*)(Vp + ((size_t)bh * NQ + kg) * HD + d4)
                                 : make_float4(0.f, 0.f, 0.f, 0.f);
            *(float4*)&Vt[kl][d4] = v;
        }
        __syncthreads();
        #pragma unroll 8
        for (int kk = 0; kk < 64; ++kk) {
            float4 vv = *(const float4*)&Vt[kk][d0];
            float p0 = Pt[q0][kk], p1 = Pt[q0 + 1][kk];
            acc0[0] = fmaf(p0, vv.x, acc0[0]); acc0[1] = fmaf(p0, vv.y, acc0[1]);
            acc0[2] = fmaf(p0, vv.z, acc0[2]); acc0[3] = fmaf(p0, vv.w, acc0[3]);
            acc1[0] = fmaf(p1, vv.x, acc1[0]); acc1[1] = fmaf(p1, vv.y, acc1[1]);
            acc1[2] = fmaf(p1, vv.z, acc1[2]); acc1[3] = fmaf(p1, vv.w, acc1[3]);
        }
    }
    int qg = qt * 64 + q0;
    if (qg < NQ)
        *(float4*)(O + ((size_t)(b * NQ + qg)) * DD + h * HD + d0) =
            make_float4(acc0[0], acc0[1], acc0[2], acc0[3]);
    if (qg + 1 < NQ)
        *(float4*)(O + ((size_t)(b * NQ + qg + 1)) * DD + h * HD + d0) =
            make_float4(acc1[0], acc1[1], acc1[2], acc1[3]);
}

// ---------------- row-block GEMM (N=256,K=256) + residual + LayerNorm on x ----------------
__global__ __launch_bounds__(256) void gemm4_res_ln(const float* __restrict__ A,
                                                    const float* __restrict__ Wt,
                                                    const float* __restrict__ bias,
                                                    const float* __restrict__ gam,
                                                    const float* __restrict__ bet,
                                                    float* __restrict__ x) {
    __shared__ float sA[4 * DD];
    __shared__ float redS[4][4], redS2[4][4];
    __shared__ float mu[4], ri[4];
    int r0 = blockIdx.x * 4;
    int j = threadIdx.x;
    ((float4*)sA)[j] = ((const float4*)(A + (size_t)r0 * DD))[j];
    __syncthreads();
    float acc0 = bias[j], acc1 = acc0, acc2 = acc0, acc3 = acc0;
    const float* wp = Wt + (size_t)j * DD;
    for (int k = 0; k < DD; k += 4) {
        float4 w  = *(const float4*)(wp + k);
        float4 a0 = *(const float4*)(sA + 0 * DD + k);
        float4 a1 = *(const float4*)(sA + 1 * DD + k);
        float4 a2 = *(const float4*)(sA + 2 * DD + k);
        float4 a3 = *(const float4*)(sA + 3 * DD + k);
        acc0 = fmaf(a0.x, w.x, acc0); acc0 = fmaf(a0.y, w.y, acc0); acc0 = fmaf(a0.z, w.z, acc0); acc0 = fmaf(a0.w, w.w, acc0);
        acc1 = fmaf(a1.x, w.x, acc1); acc1 = fmaf(a1.y, w.y, acc1); acc1 = fmaf(a1.z, w.z, acc1); acc1 = fmaf(a1.w, w.w, acc1);
        acc2 = fmaf(a2.x, w.x, acc2); acc2 = fmaf(a2.y, w.y, acc2); acc2 = fmaf(a2.z, w.z, acc2); acc2 = fmaf(a2.w, w.w, acc2);
        acc3 = fmaf(a3.x, w.x, acc3); acc3 = fmaf(a3.y, w.y, acc3); acc3 = fmaf(a3.z, w.z, acc3); acc3 = fmaf(a3.w, w.w, acc3);
    }
    float val[4];
    val[0] = x[(size_t)(r0 + 0) * DD + j] + acc0;
    val[1] = x[(size_t)(r0 + 1) * DD + j] + acc1;
    val[2] = x[(size_t)(r0 + 2) * DD + j] + acc2;
    val[3] = x[(size_t)(r0 + 3) * DD + j] + acc3;
    float s[4], s2[4];
    #pragma unroll
    for (int r = 0; r < 4; ++r) { s[r] = val[r]; s2[r] = val[r] * val[r]; }
    #pragma unroll
    for (int o2 = 32; o2 > 0; o2 >>= 1) {
        #pragma unroll
        for (int r = 0; r < 4; ++r) {
            s[r]  += __shfl_xor(s[r],  o2);
            s2[r] += __shfl_xor(s2[r], o2);
        }
    }
    int wid = j >> 6, lane = j & 63;
    if (lane == 0) {
        #pragma unroll
        for (int r = 0; r < 4; ++r) { redS[r][wid] = s[r]; redS2[r][wid] = s2[r]; }
    }
    __syncthreads();
    if (j < 4) {
        int r = j;
        float ts  = redS[r][0]  + redS[r][1]  + redS[r][2]  + redS[r][3];
        float ts2 = redS2[r][0] + redS2[r][1] + redS2[r][2] + redS2[r][3];
        float mean = ts * (1.f / DD);
        float var = ts2 * (1.f / DD) - mean * mean;
        mu[r] = mean;
        ri[r] = rsqrtf(var + 1e-5f);
    }
    __syncthreads();
    float g = gam[j], be = bet[j];
    #pragma unroll
    for (int r = 0; r < 4; ++r)
        x[(size_t)(r0 + r) * DD + j] = (val[r] - mu[r]) * ri[r] * g + be;
}

// ---------------- bilinear sample helper ----------------
template <bool TRANSPOSED>
__device__ __forceinline__ float sample_level(const float* __restrict__ f, int bv, int Hh,
                                              float un, float vn, int dth) {
    int Ww = Hh;
    float xx = (un + 1.f) * Ww * 0.5f - 0.5f;
    float yy = (vn + 1.f) * Hh * 0.5f - 0.5f;
    float x0f = floorf(xx), y0f = floorf(yy);
    int ix0 = (int)x0f, iy0 = (int)y0f;
    float wx1 = xx - x0f, wx0 = 1.f - wx1;
    float wy1 = yy - y0f, wy0 = 1.f - wy1;
    float s = 0.f;
#define TAP(IX, IY, W)                                                           \
    {                                                                            \
        int ix = (IX), iy = (IY);                                                \
        if (ix >= 0 && ix < Ww && iy >= 0 && iy < Hh) {                          \
            float v;                                                             \
            if (TRANSPOSED)                                                      \
                v = f[((size_t)bv * Hh * Ww + (size_t)iy * Ww + ix) * DD + dth]; \
            else                                                                 \
                v = f[(((size_t)bv * DD + dth) * Hh + iy) * Ww + ix];            \
            s = fmaf((W), v, s);                                                 \
        }                                                                        \
    }
    TAP(ix0,     iy0,     wy0 * wx0)
    TAP(ix0 + 1, iy0,     wy0 * wx1)
    TAP(ix0,     iy0 + 1, wy1 * wx0)
    TAP(ix0 + 1, iy0 + 1, wy1 * wx1)
#undef TAP
    return s;
}

// ---------------- project + sample + proj-GEMM + residual + LN, 4 rows/block --------------
template <bool TRANSPOSED>
__global__ __launch_bounds__(256) void sample_proj_ln(const float* __restrict__ f0,
                                                      const float* __restrict__ f1,
                                                      const float* __restrict__ f2,
                                                      const float* __restrict__ refb,
                                                      const float* __restrict__ Rm,
                                                      const float* __restrict__ Tm,
                                                      const float* __restrict__ Km,
                                                      const float* __restrict__ Wproj,
                                                      const float* __restrict__ bproj,
                                                      const float* __restrict__ gam,
                                                      const float* __restrict__ bet,
                                                      float* __restrict__ x) {
    __shared__ float sF[4 * DD];
    __shared__ float sg[32][3];
    __shared__ float redS[4][4], redS2[4][4];
    __shared__ float mu[4], ri[4];
    int r0 = blockIdx.x * 4;
    int t = threadIdx.x;
    if (t < 32) {
        int rr = t >> 3, v = t & 7;
        int row = r0 + rr;
        int b = row / NQ;
        int bv = b * VV + v;
        const float* r = refb + (size_t)row * 3;
        const float* R = Rm + (size_t)bv * 9;
        const float* T = Tm + (size_t)bv * 3;
        const float* K = Km + (size_t)bv * 9;
        float p0 = R[0] * r[0] + R[1] * r[1] + R[2] * r[2] + T[0];
        float p1 = R[3] * r[0] + R[4] * r[1] + R[5] * r[2] + T[1];
        float p2 = R[6] * r[0] + R[7] * r[1] + R[8] * r[2] + T[2];
        float z = fmaxf(p2, 0.1f);
        float u  = p0 * K[0] / z + K[2];
        float vv = p1 * K[4] / z + K[5];
        float un = 2.f * u  / (float)(W_IMG - 1) - 1.f;
        float vn = 2.f * vv / (float)(H_IMG - 1) - 1.f;
        bool m = (un > -1.f) && (un < 1.f) && (vn > -1.f) && (vn < 1.f) && (p2 > 0.f);
        sg[t][0] = un; sg[t][1] = vn; sg[t][2] = m ? 1.f : 0.f;
    }
    __syncthreads();
    #pragma unroll
    for (int rr = 0; rr < 4; ++rr) {
        int row = r0 + rr;
        int b = row / NQ;
        float acc = 0.f, cnt = 0.f;
        for (int v = 0; v < VV; ++v) {
            float m = sg[rr * 8 + v][2];
            if (m == 0.f) continue;
            cnt += 1.f;
            float un = sg[rr * 8 + v][0], vn = sg[rr * 8 + v][1];
            int bv = b * VV + v;
            float ms = sample_level<TRANSPOSED>(f0, bv, 64, un, vn, t)
                     + sample_level<TRANSPOSED>(f1, bv, 32, un, vn, t)
                     + sample_level<TRANSPOSED>(f2, bv, 16, un, vn, t);
            acc += ms * (1.f / 3.f);
        }
        sF[rr * DD + t] = acc / fmaxf(cnt, 1.f);
    }
    __syncthreads();
    float acc0 = bproj[t], acc1 = acc0, acc2 = acc0, acc3 = acc0;
    const float* wp = Wproj + (size_t)t * DD;
    for (int k = 0; k < DD; k += 4) {
        float4 w  = *(const float4*)(wp + k);
        float4 a0 = *(const float4*)(sF + 0 * DD + k);
        float4 a1 = *(const float4*)(sF + 1 * DD + k);
        float4 a2 = *(const float4*)(sF + 2 * DD + k);
        float4 a3 = *(const float4*)(sF + 3 * DD + k);
        acc0 = fmaf(a0.x, w.x, acc0); acc0 = fmaf(a0.y, w.y, acc0); acc0 = fmaf(a0.z, w.z, acc0); acc0 = fmaf(a0.w, w.w, acc0);
        acc1 = fmaf(a1.x, w.x, acc1); acc1 = fmaf(a1.y, w.y, acc1); acc1 = fmaf(a1.z, w.z, acc1); acc1 = fmaf(a1.w, w.w, acc1);
        acc2 = fmaf(a2.x, w.x, acc2); acc2 = fmaf(a2.y, w.y, acc2); acc2 = fmaf(a2.z, w.z, acc2); acc2 = fmaf(a2.w, w.w, acc2);
        acc3 = fmaf(a3.x, w.x, acc3); acc3 = fmaf(a3.y, w.y, acc3); acc3 = fmaf(a3.z, w.z, acc3); acc3 = fmaf(a3.w, w.w, acc3);
    }
    float val[4];
    val[0] = x[(size_t)(r0 + 0) * DD + t] + acc0;
    val[1] = x[(size_t)(r0 + 1) * DD + t] + acc1;
    val[2] = x[(size_t)(r0 + 2) * DD + t] + acc2;
    val[3] = x[(size_t)(r0 + 3) * DD + t] + acc3;
    float s[4], s2[4];
    #pragma unroll
    for (int r = 0; r < 4; ++r) { s[r] = val[r]; s2[r] = val[r] * val[r]; }
    #pragma unroll
    for (int o2 = 32; o2 > 0; o2 >>= 1) {
        #pragma unroll
        for (int r = 0; r < 4; ++r) {
            s[r]  += __shfl_xor(s[r],  o2);
            s2[r] += __shfl_xor(s2[r], o2);
        }
    }
    int wid = t >> 6, lane = t & 63;
    if (lane == 0) {
        #pragma unroll
        for (int r = 0; r < 4; ++r) { redS[r][wid] = s[r]; redS2[r][wid] = s2[r]; }
    }
    __syncthreads();
    if (t < 4) {
        int r = t;
        float ts  = redS[r][0]  + redS[r][1]  + redS[r][2]  + redS[r][3];
        float ts2 = redS2[r][0] + redS2[r][1] + redS2[r][2] + redS2[r][3];
        float mean = ts * (1.f / DD);
        float var = ts2 * (1.f / DD) - mean * mean;
        mu[r] = mean;
        ri[r] = rsqrtf(var + 1e-5f);
    }
    __syncthreads();
    float g = gam[t], be = bet[t];
    #pragma unroll
    for (int r = 0; r < 4; ++r)
        x[(size_t)(r0 + r) * DD + t] = (val[r] - mu[r]) * ri[r] * g + be;
}

// ---------------- generic tiled GEMM for FFN. MODE 0 plain, 1 relu. grid (21, N/64, KS) ----
template <int MODE>
__global__ __launch_bounds__(256) void gemm_tile(const float* __restrict__ A,
                                                 const float* __restrict__ W,
                                                 const float* __restrict__ bias,
                                                 float* __restrict__ C,
                                                 int Ktot, int Kper, int Nout) {
    __shared__ float At[32][34];
    __shared__ float Wt[32][68];
    int t = threadIdx.x;
    int m0 = blockIdx.x * 32;
    int n0 = blockIdx.y * 64;
    int kz = blockIdx.z;
    int kofs = kz * Kper;
    int tx = t & 15, ty = t >> 4;
    int nc = n0 + tx * 4;
    float acc0[4], acc1[4];
    {
        float4 bv = make_float4(0.f, 0.f, 0.f, 0.f);
        if (bias && kz == 0) bv = *(const float4*)(bias + nc);
        acc0[0] = bv.x; acc0[1] = bv.y; acc0[2] = bv.z; acc0[3] = bv.w;
        acc1[0] = bv.x; acc1[1] = bv.y; acc1[2] = bv.z; acc1[3] = bv.w;
    }
    int am = t >> 3, ak4 = (t & 7) * 4;
    int ktiles = Kper >> 5;
    for (int kt = 0; kt < ktiles; ++kt) {
        int kk = kofs + kt * 32;
        __syncthreads();
        {
            float4 v = *(const float4*)(A + (size_t)(m0 + am) * Ktot + kk + ak4);
            At[ak4 + 0][am] = v.x; At[ak4 + 1][am] = v.y;
            At[ak4 + 2][am] = v.z; At[ak4 + 3][am] = v.w;
        }
        #pragma unroll
        for (int s = 0; s < 2; ++s) {
            int idx = t + s * 256;
            int wn = idx >> 3, wk4 = (idx & 7) * 4;
            float4 v = *(const float4*)(W + (size_t)(n0 + wn) * Ktot + kk + wk4);
            Wt[wk4 + 0][wn] = v.x; Wt[wk4 + 1][wn] = v.y;
            Wt[wk4 + 2][wn] = v.z; Wt[wk4 + 3][wn] = v.w;
        }
        __syncthreads();
        #pragma unroll
        for (int k = 0; k < 32; ++k) {
            float2 av = *(const float2*)&At[k][ty * 2];
            float4 wv = *(const float4*)&Wt[k][tx * 4];
            acc0[0] = fmaf(av.x, wv.x, acc0[0]); acc0[1] = fmaf(av.x, wv.y, acc0[1]);
            acc0[2] = fmaf(av.x, wv.z, acc0[2]); acc0[3] = fmaf(av.x, wv.w, acc0[3]);
            acc1[0] = fmaf(av.y, wv.x, acc1[0]); acc1[1] = fmaf(av.y, wv.y, acc1[1]);
            acc1[2] = fmaf(av.y, wv.z, acc1[2]); acc1[3] = fmaf(av.y, wv.w, acc1[3]);
        }
    }
    if (MODE == 1) {
        #pragma unroll
        for (int j = 0; j < 4; ++j) { acc0[j] = fmaxf(acc0[j], 0.f); acc1[j] = fmaxf(acc1[j], 0.f); }
    }
    int mr = m0 + ty * 2;
    float* Cb = C + (size_t)kz * MROWS * Nout;
    *(float4*)(Cb + (size_t)mr * Nout + nc)       = make_float4(acc0[0], acc0[1], acc0[2], acc0[3]);
    *(float4*)(Cb + (size_t)(mr + 1) * Nout + nc) = make_float4(acc1[0], acc1[1], acc1[2], acc1[3]);
}

// ---------------- residual + LN over NP k-split partials; xq = out + qp ----------------
template <int NP>
__global__ __launch_bounds__(256) void ln_res(float* __restrict__ x,
                                              const float* __restrict__ C,
                                              const float* __restrict__ gam,
                                              const float* __restrict__ bet,
                                              const float* __restrict__ qp,
                                              float* __restrict__ xq) {
    __shared__ float redS[4][4], redS2[4][4];
    __shared__ float mu[4], ri[4];
    int r0 = blockIdx.x * 4;
    int j = threadIdx.x;
    float val[4];
    #pragma unroll
    for (int r = 0; r < 4; ++r) {
        float a = x[(size_t)(r0 + r) * DD + j];
        #pragma unroll
        for (int p = 0; p < NP; ++p) a += C[(size_t)p * MROWS * DD + (size_t)(r0 + r) * DD + j];
        val[r] = a;
    }
    float s[4], s2[4];
    #pragma unroll
    for (int r = 0; r < 4; ++r) { s[r] = val[r]; s2[r] = val[r] * val[r]; }
    #pragma unroll
    for (int o = 32; o > 0; o >>= 1) {
        #pragma unroll
        for (int r = 0; r < 4; ++r) {
            s[r]  += __shfl_xor(s[r],  o);
            s2[r] += __shfl_xor(s2[r], o);
        }
    }
    int wid = j >> 6, lane = j & 63;
    if (lane == 0) {
        #pragma unroll
        for (int r = 0; r < 4; ++r) { redS[r][wid] = s[r]; redS2[r][wid] = s2[r]; }
    }
    __syncthreads();
    if (j < 4) {
        int r = j;
        float ts  = redS[r][0]  + redS[r][1]  + redS[r][2]  + redS[r][3];
        float ts2 = redS2[r][0] + redS2[r][1] + redS2[r][2] + redS2[r][3];
        float mean = ts * (1.f / DD);
        float var = ts2 * (1.f / DD) - mean * mean;
        mu[r] = mean;
        ri[r] = rsqrtf(var + 1e-5f);
    }
    __syncthreads();
    float g = gam[j], be = bet[j];
    #pragma unroll
    for (int r = 0; r < 4; ++r) {
        float o = (val[r] - mu[r]) * ri[r] * g + be;
        x[(size_t)(r0 + r) * DD + j] = o;
        if (qp) xq[(size_t)(r0 + r) * DD + j] = o + qp[(size_t)(r0 + r) * DD + j];
    }
}

// ---------------- fused pose MLP + heads, 4 rows/block ----------------
__global__ __launch_bounds__(256) void pose_fused(const float* __restrict__ x,
                                                  const float* __restrict__ W0, const float* __restrict__ b0,
                                                  const float* __restrict__ W1p, const float* __restrict__ b1p,
                                                  const float* __restrict__ W2p, const float* __restrict__ b2p,
                                                  const float* __restrict__ cW, const float* __restrict__ cb,
                                                  float* __restrict__ refb, float* __restrict__ outp) {
    __shared__ float sX[4 * DD];
    __shared__ float sH[4 * DD];
    __shared__ float red[4][4][4];
    int r0 = blockIdx.x * 4;
    int tid = threadIdx.x;
    ((float4*)sX)[tid] = ((const float4*)(x + (size_t)r0 * DD))[tid];
    __syncthreads();
    {
        float a0 = b0[tid], a1 = a0, a2 = a0, a3 = a0;
        const float* wp = W0 + (size_t)tid * DD;
        for (int k = 0; k < DD; k += 4) {
            float4 w  = *(const float4*)(wp + k);
            float4 x0 = *(const float4*)(sX + 0 * DD + k);
            float4 x1 = *(const float4*)(sX + 1 * DD + k);
            float4 x2 = *(const float4*)(sX + 2 * DD + k);
            float4 x3 = *(const float4*)(sX + 3 * DD + k);
            a0 = fmaf(x0.x, w.x, a0); a0 = fmaf(x0.y, w.y, a0); a0 = fmaf(x0.z, w.z, a0); a0 = fmaf(x0.w, w.w, a0);
            a1 = fmaf(x1.x, w.x, a1); a1 = fmaf(x1.y, w.y, a1); a1 = fmaf(x1.z, w.z, a1); a1 = fmaf(x1.w, w.w, a1);
            a2 = fmaf(x2.x, w.x, a2); a2 = fmaf(x2.y, w.y, a2); a2 = fmaf(x2.z, w.z, a2); a2 = fmaf(x2.w, w.w, a2);
            a3 = fmaf(x3.x, w.x, a3); a3 = fmaf(x3.y, w.y, a3); a3 = fmaf(x3.z, w.z, a3); a3 = fmaf(x3.w, w.w, a3);
        }
        sH[0 * DD + tid] = fmaxf(a0, 0.f);
        sH[1 * DD + tid] = fmaxf(a1, 0.f);
        sH[2 * DD + tid] = fmaxf(a2, 0.f);
        sH[3 * DD + tid] = fmaxf(a3, 0.f);
    }
    __syncthreads();
    float h[4];
    {
        float a0 = b1p[tid], a1 = a0, a2 = a0, a3 = a0;
        const float* wp = W1p + (size_t)tid * DD;
        for (int k = 0; k < DD; k += 4) {
            float4 w  = *(const float4*)(wp + k);
            float4 x0 = *(const float4*)(sH + 0 * DD + k);
            float4 x1 = *(const float4*)(sH + 1 * DD + k);
            float4 x2 = *(const float4*)(sH + 2 * DD + k);
            float4 x3 = *(const float4*)(sH + 3 * DD + k);
            a0 = fmaf(x0.x, w.x, a0); a0 = fmaf(x0.y, w.y, a0); a0 = fmaf(x0.z, w.z, a0); a0 = fmaf(x0.w, w.w, a0);
            a1 = fmaf(x1.x, w.x, a1); a1 = fmaf(x1.y, w.y, a1); a1 = fmaf(x1.z, w.z, a1); a1 = fmaf(x1.w, w.w, a1);
            a2 = fmaf(x2.x, w.x, a2); a2 = fmaf(x2.y, w.y, a2); a2 = fmaf(x2.z, w.z, a2); a2 = fmaf(x2.w, w.w, a2);
            a3 = fmaf(x3.x, w.x, a3); a3 = fmaf(x3.y, w.y, a3); a3 = fmaf(x3.z, w.z, a3); a3 = fmaf(x3.w, w.w, a3);
        }
        h[0] = fmaxf(a0, 0.f); h[1] = fmaxf(a1, 0.f); h[2] = fmaxf(a2, 0.f); h[3] = fmaxf(a3, 0.f);
    }
    float w2a = W2p[tid], w2b = W2p[DD + tid], w2c = W2p[2 * DD + tid], cw = cW[tid];
    float v[4][4];
    #pragma unroll
    for (int r = 0; r < 4; ++r) {
        v[r][0] = h[r] * w2a;
        v[r][1] = h[r] * w2b;
        v[r][2] = h[r] * w2c;
        v[r][3] = sX[r * DD + tid] * cw;
    }
    #pragma unroll
    for (int o2 = 32; o2 > 0; o2 >>= 1) {
        #pragma unroll
        for (int r = 0; r < 4; ++r) {
            #pragma unroll
            for (int c = 0; c < 4; ++c) v[r][c] += __shfl_xor(v[r][c], o2);
        }
    }
    int wid = tid >> 6, lane = tid & 63;
    if (lane == 0) {
        #pragma unroll
        for (int r = 0; r < 4; ++r) {
            #pragma unroll
            for (int c = 0; c < 4; ++c) red[r][c][wid] = v[r][c];
        }
    }
    __syncthreads();
    if (tid < 4) {
        int r = tid;
        float d0 = red[r][0][0] + red[r][0][1] + red[r][0][2] + red[r][0][3] + b2p[0];
        float d1 = red[r][1][0] + red[r][1][1] + red[r][1][2] + red[r][1][3] + b2p[1];
        float d2 = red[r][2][0] + red[r][2][1] + red[r][2][2] + red[r][2][3] + b2p[2];
        float cl = red[r][3][0] + red[r][3][1] + red[r][3][2] + red[r][3][3] + cb[0];
        int row = r0 + r;
        float rx = refb[(size_t)row * 3 + 0] + d0;
        float ry = refb[(size_t)row * 3 + 1] + d1;
        float rz = refb[(size_t)row * 3 + 2] + d2;
        refb[(size_t)row * 3 + 0] = rx;
        refb[(size_t)row * 3 + 1] = ry;
        refb[(size_t)row * 3 + 2] = rz;
        outp[(size_t)row * 4 + 0] = cl;
        outp[(size_t)row * 4 + 1] = rx;
        outp[(size_t)row * 4 + 2] = ry;
        outp[(size_t)row * 4 + 3] = rz;
    }
}

extern "C" void kernel_launch(void* const* d_in, const int* in_sizes, int n_in,
                              void* d_out, int out_size, void* d_ws, size_t ws_size,
                              hipStream_t stream) {
    const float* tgt       = (const float*)d_in[0];
    const float* query_pos = (const float*)d_in[1];
    const float* refpts    = (const float*)d_in[2];
    const float* feat0     = (const float*)d_in[3];
    const float* feat1     = (const float*)d_in[4];
    const float* feat2     = (const float*)d_in[5];
    const float* camR      = (const float*)d_in[6];
    const float* camT      = (const float*)d_in[7];
    const float* camK      = (const float*)d_in[8];
    const float* Wqkv      = (const float*)d_in[9];
    const float* bqkv      = (const float*)d_in[10];
    const float* Wo        = (const float*)d_in[11];
    const float* bo        = (const float*)d_in[12];
    const float* ln1_g     = (const float*)d_in[13];
    const float* ln1_b     = (const float*)d_in[14];
    const float* Wproj     = (const float*)d_in[15];
    const float* bproj     = (const float*)d_in[16];
    const float* pn_g      = (const float*)d_in[17];
    const float* pn_b      = (const float*)d_in[18];
    const float* W1        = (const float*)d_in[19];
    const float* b1        = (const float*)d_in[20];
    const float* W2        = (const float*)d_in[21];
    const float* b2        = (const float*)d_in[22];
    const float* ln2_g     = (const float*)d_in[23];
    const float* ln2_b     = (const float*)d_in[24];
    const float* pose_W0   = (const float*)d_in[25];
    const float* pose_b0   = (const float*)d_in[26];
    const float* pose_W1   = (const float*)d_in[27];
    const float* pose_b1   = (const float*)d_in[28];
    const float* pose_W2   = (const float*)d_in[29];
    const float* pose_b2   = (const float*)d_in[30];
    const float* cls_W     = (const float*)d_in[31];
    const float* cls_b     = (const float*)d_in[32];
    float* out = (float*)d_out;

    float* w = (float*)d_ws;
    size_t off = 0;
    auto alloc = [&](size_t n) { float* p = w + off; off += n; return p; };
    float* x      = alloc((size_t)BQ * DD);
    float* xq     = alloc((size_t)BQ * DD);
    float* Qp     = alloc((size_t)BB * HEADS * NQ * HD);
    float* Kp     = alloc((size_t)BB * HEADS * NQ * HD);
    float* Vp     = alloc((size_t)BB * HEADS * NQ * HD);
    float* S      = alloc((size_t)BB * HEADS * SP * SP);
    float* attn_o = alloc((size_t)BQ * DD);
    float* ffh    = alloc((size_t)BQ * FF);
    float* ctmp   = alloc((size_t)4 * BQ * DD);
    float* refb   = alloc((size_t)BQ * 3 + 64);
    size_t base_floats = off;
    size_t featT_floats = (size_t)BB * VV * DD * (64 * 64 + 32 * 32 + 16 * 16);
    bool useT = ws_size >= (base_floats + featT_floats) * sizeof(float);
    float *fT0 = nullptr, *fT1 = nullptr, *fT2 = nullptr;
    if (useT) {
        fT0 = alloc((size_t)BB * VV * 64 * 64 * DD);
        fT1 = alloc((size_t)BB * VV * 32 * 32 * DD);
        fT2 = alloc((size_t)BB * VV * 16 * 16 * DD);
    }

    init_k<<<BQ * DD / 4 / 256, 256, 0, stream>>>(tgt, query_pos, refpts, x, xq, refb);
    if (useT)
        transpose_all<<<5376, 256, 0, stream>>>(feat0, feat1, feat2, fT0, fT1, fT2);

    for (int l = 0; l < NL; ++l) {
        qkv_tile<<<dim3(21, 12), 256, 0, stream>>>(
            xq, x, Wqkv + (size_t)l * 3 * DD * DD, bqkv + (size_t)l * 3 * DD, Qp, Kp, Vp);
        attn_scores<<<dim3(BB * HEADS, 6), 256, 0, stream>>>(Qp, Kp, S);
        attn_pv_sm<<<dim3(BB * HEADS, 6), 256, 0, stream>>>(S, Vp, attn_o);
        gemm4_res_ln<<<BQ / 4, 256, 0, stream>>>(
            attn_o, Wo + (size_t)l * DD * DD, bo + (size_t)l * DD,
            ln1_g + (size_t)l * DD, ln1_b + (size_t)l * DD, x);
        if (useT)
            sample_proj_ln<true><<<BQ / 4, 256, 0, stream>>>(
                fT0, fT1, fT2, refb, camR, camT, camK,
                Wproj + (size_t)l * DD * DD, bproj + (size_t)l * DD,
                pn_g + (size_t)l * DD, pn_b + (size_t)l * DD, x);
        else
            sample_proj_ln<false><<<BQ / 4, 256, 0, stream>>>(
                feat0, feat1, feat2, refb, camR, camT, camK,
                Wproj + (size_t)l * DD * DD, bproj + (size_t)l * DD,
                pn_g + (size_t)l * DD, pn_b + (size_t)l * DD, x);
        gemm_tile<1><<<dim3(21, 16, 1), 256, 0, stream>>>(
            x, W1 + (size_t)l * FF * DD, b1 + (size_t)l * FF, ffh, DD, DD, FF);
        gemm_tile<0><<<dim3(21, 4, 4), 256, 0, stream>>>(
            ffh, W2 + (size_t)l * DD * FF, b2 + (size_t)l * DD, ctmp, FF, FF / 4, DD);
        ln_res<4><<<BQ / 4, 256, 0, stream>>>(
            x, ctmp, ln2_g + (size_t)l * DD, ln2_b + (size_t)l * DD, query_pos, xq);
        pose_fused<<<BQ / 4, 256, 0, stream>>>(
            x, pose_W0, pose_b0, pose_W1, pose_b1, pose_W2, pose_b2, cls_W, cls_b,
            refb, out + (size_t)l * BQ * 4);
    }
}

// Round 8
// 1052.485 us; speedup vs baseline: 6.3647x; 1.6208x over previous
//
#include <hip/hip_runtime.h>
#include <math.h>

#define BB 2
#define VV 8
#define NQ 336
#define DD 256
#define HEADS 8
#define HD 32
#define FF 1024
#define NL 6
#define BQ (BB*NQ)
#define W_IMG 512
#define H_IMG 512
#define SP 384
#define MROWS BQ

// ================= job: 64x64 transpose tile =================
__device__ __forceinline__ void job_transpose(int b,
                                              const float* __restrict__ f0,
                                              const float* __restrict__ f1,
                                              const float* __restrict__ f2,
                                              float* __restrict__ o0,
                                              float* __restrict__ o1,
                                              float* __restrict__ o2) {
    const float* src; float* dst; int HW, ptiles;
    if (b < 4096)      { src = f0; dst = o0; HW = 4096; ptiles = 64; }
    else if (b < 5120) { b -= 4096; src = f1; dst = o1; HW = 1024; ptiles = 16; }
    else               { b -= 5120; src = f2; dst = o2; HW = 256;  ptiles = 4;  }
    int cg = b & 3;
    int pt = (b >> 2) % ptiles;
    int bv = (b >> 2) / ptiles;
    int d0 = cg * 64, p0 = pt * 64;
    __shared__ float tile[64][65];
    int tid = threadIdx.x;
    int t4 = tid >> 4, t15 = tid & 15;
    #pragma unroll
    for (int pass = 0; pass < 4; ++pass) {
        int d = pass * 16 + t4;
        int p = t15 * 4;
        float4 v = *(const float4*)(src + ((size_t)(bv * DD + d0 + d)) * HW + p0 + p);
        tile[d][p] = v.x; tile[d][p + 1] = v.y; tile[d][p + 2] = v.z; tile[d][p + 3] = v.w;
    }
    __syncthreads();
    #pragma unroll
    for (int pass = 0; pass < 4; ++pass) {
        int p = pass * 16 + t4;
        int d = t15 * 4;
        float4 v = make_float4(tile[d][p], tile[d + 1][p], tile[d + 2][p], tile[d + 3][p]);
        *(float4*)(dst + ((size_t)bv * HW + p0 + p) * DD + d0 + d) = v;
    }
}

// ================= transpose (5376 blocks) + init (168 blocks) =================
__global__ __launch_bounds__(256) void transpose_init(const float* __restrict__ f0,
                                                      const float* __restrict__ f1,
                                                      const float* __restrict__ f2,
                                                      float* __restrict__ o0,
                                                      float* __restrict__ o1,
                                                      float* __restrict__ o2,
                                                      const float* __restrict__ tgt,
                                                      const float* __restrict__ qp,
                                                      const float* __restrict__ refpts,
                                                      float* __restrict__ x,
                                                      float* __restrict__ xq,
                                                      float* __restrict__ refb,
                                                      int tbase) {
    int b = blockIdx.x;
    if (b < tbase) {
        job_transpose(b, f0, f1, f2, o0, o1, o2);
    } else {
        int i = (b - tbase) * 256 + threadIdx.x;   // 168*256 = 43008 = BQ*DD/4
        float4 tv = ((const float4*)tgt)[i];
        float4 qv = ((const float4*)qp)[i];
        ((float4*)x)[i] = tv;
        ((float4*)xq)[i] = make_float4(tv.x + qv.x, tv.y + qv.y, tv.z + qv.z, tv.w + qv.w);
        if (i < BQ * 3) refb[i] = refpts[i];
    }
}

// ================= job: 32x64 qkv tile, head-packed output =================
__device__ __forceinline__ void job_qkv(float* sm, int bid,
                                        const float* __restrict__ Aq,
                                        const float* __restrict__ Ax,
                                        const float* __restrict__ W,
                                        const float* __restrict__ bias,
                                        float* __restrict__ Qp,
                                        float* __restrict__ Kp,
                                        float* __restrict__ Vp) {
    float* At = sm;            // [32][34]
    float* Wt = sm + 1088;     // [32][68]
    int t = threadIdx.x;
    int m0 = (bid % 21) * 32;
    int ncol = bid / 21;
    int n0 = ncol * 64;
    const float* A = (ncol < 8) ? Aq : Ax;
    int tx = t & 15, ty = t >> 4;
    int nc = n0 + tx * 4;
    float acc0[4], acc1[4];
    {
        float4 bv = *(const float4*)(bias + nc);
        acc0[0] = bv.x; acc0[1] = bv.y; acc0[2] = bv.z; acc0[3] = bv.w;
        acc1[0] = bv.x; acc1[1] = bv.y; acc1[2] = bv.z; acc1[3] = bv.w;
    }
    int am = t >> 3, ak4 = (t & 7) * 4;
    for (int kt = 0; kt < 8; ++kt) {
        int kk = kt * 32;
        __syncthreads();
        {
            float4 v = *(const float4*)(A + (size_t)(m0 + am) * DD + kk + ak4);
            At[(ak4 + 0) * 34 + am] = v.x; At[(ak4 + 1) * 34 + am] = v.y;
            At[(ak4 + 2) * 34 + am] = v.z; At[(ak4 + 3) * 34 + am] = v.w;
        }
        #pragma unroll
        for (int s = 0; s < 2; ++s) {
            int idx = t + s * 256;
            int wn = idx >> 3, wk4 = (idx & 7) * 4;
            float4 v = *(const float4*)(W + (size_t)(n0 + wn) * DD + kk + wk4);
            Wt[(wk4 + 0) * 68 + wn] = v.x; Wt[(wk4 + 1) * 68 + wn] = v.y;
            Wt[(wk4 + 2) * 68 + wn] = v.z; Wt[(wk4 + 3) * 68 + wn] = v.w;
        }
        __syncthreads();
        #pragma unroll
        for (int k = 0; k < 32; ++k) {
            float2 av = *(const float2*)&At[k * 34 + ty * 2];
            float4 wv = *(const float4*)&Wt[k * 68 + tx * 4];
            acc0[0] = fmaf(av.x, wv.x, acc0[0]); acc0[1] = fmaf(av.x, wv.y, acc0[1]);
            acc0[2] = fmaf(av.x, wv.z, acc0[2]); acc0[3] = fmaf(av.x, wv.w, acc0[3]);
            acc1[0] = fmaf(av.y, wv.x, acc1[0]); acc1[1] = fmaf(av.y, wv.y, acc1[1]);
            acc1[2] = fmaf(av.y, wv.z, acc1[2]); acc1[3] = fmaf(av.y, wv.w, acc1[3]);
        }
    }
    int mr = m0 + ty * 2;
    int kind = nc >> 8;
    float* base = kind == 0 ? Qp : (kind == 1 ? Kp : Vp);
    int h = (nc >> 5) & 7, d4 = nc & 31;
    #pragma unroll
    for (int i = 0; i < 2; ++i) {
        int m = mr + i;
        int b = m / NQ, q = m - b * NQ;
        float* p = base + ((size_t)((b << 3) + h) * NQ + q) * HD + d4;
        float* src = i == 0 ? acc0 : acc1;
        *(float4*)p = make_float4(src[0], src[1], src[2], src[3]);
    }
}

// ================= job: pose MLP + heads for 4 rows =================
__device__ __forceinline__ void job_pose(float* sm, int job,
                                         const float* __restrict__ x,
                                         const float* __restrict__ W0, const float* __restrict__ b0,
                                         const float* __restrict__ W1p, const float* __restrict__ b1p,
                                         const float* __restrict__ W2p, const float* __restrict__ b2p,
                                         const float* __restrict__ cW, const float* __restrict__ cb,
                                         float* __restrict__ refb, float* __restrict__ outp) {
    float* sX  = sm;          // 1024
    float* sH  = sm + 1024;   // 1024
    float* red = sm + 2048;   // 64
    int r0 = job * 4;
    int tid = threadIdx.x;
    ((float4*)sX)[tid] = ((const float4*)(x + (size_t)r0 * DD))[tid];
    __syncthreads();
    {
        float a0 = b0[tid], a1 = a0, a2 = a0, a3 = a0;
        const float* wp = W0 + (size_t)tid * DD;
        for (int k = 0; k < DD; k += 4) {
            float4 w  = *(const float4*)(wp + k);
            float4 x0 = *(const float4*)(sX + 0 * DD + k);
            float4 x1 = *(const float4*)(sX + 1 * DD + k);
            float4 x2 = *(const float4*)(sX + 2 * DD + k);
            float4 x3 = *(const float4*)(sX + 3 * DD + k);
            a0 = fmaf(x0.x, w.x, a0); a0 = fmaf(x0.y, w.y, a0); a0 = fmaf(x0.z, w.z, a0); a0 = fmaf(x0.w, w.w, a0);
            a1 = fmaf(x1.x, w.x, a1); a1 = fmaf(x1.y, w.y, a1); a1 = fmaf(x1.z, w.z, a1); a1 = fmaf(x1.w, w.w, a1);
            a2 = fmaf(x2.x, w.x, a2); a2 = fmaf(x2.y, w.y, a2); a2 = fmaf(x2.z, w.z, a2); a2 = fmaf(x2.w, w.w, a2);
            a3 = fmaf(x3.x, w.x, a3); a3 = fmaf(x3.y, w.y, a3); a3 = fmaf(x3.z, w.z, a3); a3 = fmaf(x3.w, w.w, a3);
        }
        sH[0 * DD + tid] = fmaxf(a0, 0.f);
        sH[1 * DD + tid] = fmaxf(a1, 0.f);
        sH[2 * DD + tid] = fmaxf(a2, 0.f);
        sH[3 * DD + tid] = fmaxf(a3, 0.f);
    }
    __syncthreads();
    float h[4];
    {
        float a0 = b1p[tid], a1 = a0, a2 = a0, a3 = a0;
        const float* wp = W1p + (size_t)tid * DD;
        for (int k = 0; k < DD; k += 4) {
            float4 w  = *(const float4*)(wp + k);
            float4 x0 = *(const float4*)(sH + 0 * DD + k);
            float4 x1 = *(const float4*)(sH + 1 * DD + k);
            float4 x2 = *(const float4*)(sH + 2 * DD + k);
            float4 x3 = *(const float4*)(sH + 3 * DD + k);
            a0 = fmaf(x0.x, w.x, a0); a0 = fmaf(x0.y, w.y, a0); a0 = fmaf(x0.z, w.z, a0); a0 = fmaf(x0.w, w.w, a0);
            a1 = fmaf(x1.x, w.x, a1); a1 = fmaf(x1.y, w.y, a1); a1 = fmaf(x1.z, w.z, a1); a1 = fmaf(x1.w, w.w, a1);
            a2 = fmaf(x2.x, w.x, a2); a2 = fmaf(x2.y, w.y, a2); a2 = fmaf(x2.z, w.z, a2); a2 = fmaf(x2.w, w.w, a2);
            a3 = fmaf(x3.x, w.x, a3); a3 = fmaf(x3.y, w.y, a3); a3 = fmaf(x3.z, w.z, a3); a3 = fmaf(x3.w, w.w, a3);
        }
        h[0] = fmaxf(a0, 0.f); h[1] = fmaxf(a1, 0.f); h[2] = fmaxf(a2, 0.f); h[3] = fmaxf(a3, 0.f);
    }
    float w2a = W2p[tid], w2b = W2p[DD + tid], w2c = W2p[2 * DD + tid], cw = cW[tid];
    float v[4][4];
    #pragma unroll
    for (int r = 0; r < 4; ++r) {
        v[r][0] = h[r] * w2a;
        v[r][1] = h[r] * w2b;
        v[r][2] = h[r] * w2c;
        v[r][3] = sX[r * DD + tid] * cw;
    }
    #pragma unroll
    for (int o2 = 32; o2 > 0; o2 >>= 1) {
        #pragma unroll
        for (int r = 0; r < 4; ++r) {
            #pragma unroll
            for (int c = 0; c < 4; ++c) v[r][c] += __shfl_xor(v[r][c], o2);
        }
    }
    int wid = tid >> 6, lane = tid & 63;
    if (lane == 0) {
        #pragma unroll
        for (int r = 0; r < 4; ++r) {
            #pragma unroll
            for (int c = 0; c < 4; ++c) red[(r * 4 + c) * 4 + wid] = v[r][c];
        }
    }
    __syncthreads();
    if (tid < 4) {
        int r = tid;
        float d0 = red[(r * 4 + 0) * 4 + 0] + red[(r * 4 + 0) * 4 + 1] + red[(r * 4 + 0) * 4 + 2] + red[(r * 4 + 0) * 4 + 3] + b2p[0];
        float d1 = red[(r * 4 + 1) * 4 + 0] + red[(r * 4 + 1) * 4 + 1] + red[(r * 4 + 1) * 4 + 2] + red[(r * 4 + 1) * 4 + 3] + b2p[1];
        float d2 = red[(r * 4 + 2) * 4 + 0] + red[(r * 4 + 2) * 4 + 1] + red[(r * 4 + 2) * 4 + 2] + red[(r * 4 + 2) * 4 + 3] + b2p[2];
        float cl = red[(r * 4 + 3) * 4 + 0] + red[(r * 4 + 3) * 4 + 1] + red[(r * 4 + 3) * 4 + 2] + red[(r * 4 + 3) * 4 + 3] + cb[0];
        int row = r0 + r;
        float rx = refb[(size_t)row * 3 + 0] + d0;
        float ry = refb[(size_t)row * 3 + 1] + d1;
        float rz = refb[(size_t)row * 3 + 2] + d2;
        refb[(size_t)row * 3 + 0] = rx;
        refb[(size_t)row * 3 + 1] = ry;
        refb[(size_t)row * 3 + 2] = rz;
        outp[(size_t)row * 4 + 0] = cl;
        outp[(size_t)row * 4 + 1] = rx;
        outp[(size_t)row * 4 + 2] = ry;
        outp[(size_t)row * 4 + 3] = rz;
    }
}

// ================= fused dispatch A: qkv (252) + pose of prev layer (168) =================
__global__ __launch_bounds__(256) void qkv_pose(const float* __restrict__ xq,
                                                const float* __restrict__ x,
                                                const float* __restrict__ Wqkv,
                                                const float* __restrict__ bqkv,
                                                float* __restrict__ Qp,
                                                float* __restrict__ Kp,
                                                float* __restrict__ Vp,
                                                const float* __restrict__ pW0, const float* __restrict__ pb0,
                                                const float* __restrict__ pW1, const float* __restrict__ pb1,
                                                const float* __restrict__ pW2, const float* __restrict__ pb2,
                                                const float* __restrict__ cW, const float* __restrict__ cb,
                                                float* __restrict__ refb, float* __restrict__ outp) {
    __shared__ float sm[3264];
    if (blockIdx.x < 252)
        job_qkv(sm, blockIdx.x, xq, x, Wqkv, bqkv, Qp, Kp, Vp);
    else
        job_pose(sm, blockIdx.x - 252, x, pW0, pb0, pW1, pb1, pW2, pb2, cW, cb, refb, outp);
}

// standalone pose (tail)
__global__ __launch_bounds__(256) void pose_only(const float* __restrict__ x,
                                                 const float* __restrict__ pW0, const float* __restrict__ pb0,
                                                 const float* __restrict__ pW1, const float* __restrict__ pb1,
                                                 const float* __restrict__ pW2, const float* __restrict__ pb2,
                                                 const float* __restrict__ cW, const float* __restrict__ cb,
                                                 float* __restrict__ refb, float* __restrict__ outp) {
    __shared__ float sm[2112];
    job_pose(sm, blockIdx.x, x, pW0, pb0, pW1, pb1, pW2, pb2, cW, cb, refb, outp);
}

// ================= attention scores (scaled). grid (16, 6) =================
__global__ __launch_bounds__(256) void attn_scores(const float* __restrict__ Qp,
                                                   const float* __restrict__ Kp,
                                                   float* __restrict__ S) {
    int bh = blockIdx.x, qt = blockIdx.y;
    __shared__ float QT[32][68];
    __shared__ float KT[32][68];
    int t = threadIdx.x;
    const float scale = 0.17677669529663687f;
    const float* Qb = Qp + (size_t)bh * NQ * HD;
    const float* Kb = Kp + (size_t)bh * NQ * HD;
    #pragma unroll
    for (int s = 0; s < 2; ++s) {
        int idx = t + s * 256;
        int ql = idx >> 3, d4 = (idx & 7) * 4;
        int qg = qt * 64 + ql;
        float4 v = (qg < NQ) ? *(const float4*)(Qb + (size_t)qg * HD + d4)
                             : make_float4(0.f, 0.f, 0.f, 0.f);
        QT[d4 + 0][ql] = v.x * scale; QT[d4 + 1][ql] = v.y * scale;
        QT[d4 + 2][ql] = v.z * scale; QT[d4 + 3][ql] = v.w * scale;
    }
    int tx = t & 15, ty = t >> 4;
    for (int kt = 0; kt < 6; ++kt) {
        __syncthreads();
        #pragma unroll
        for (int s = 0; s < 2; ++s) {
            int idx = t + s * 256;
            int kl = idx >> 3, d4 = (idx & 7) * 4;
            int kg = kt * 64 + kl;
            float4 v = (kg < NQ) ? *(const float4*)(Kb + (size_t)kg * HD + d4)
                                 : make_float4(0.f, 0.f, 0.f, 0.f);
            KT[d4 + 0][kl] = v.x; KT[d4 + 1][kl] = v.y;
            KT[d4 + 2][kl] = v.z; KT[d4 + 3][kl] = v.w;
        }
        __syncthreads();
        float a0[4] = {0, 0, 0, 0}, a1[4] = {0, 0, 0, 0}, a2[4] = {0, 0, 0, 0}, a3[4] = {0, 0, 0, 0};
        #pragma unroll
        for (int k = 0; k < 32; ++k) {
            float4 qv = *(const float4*)&QT[k][ty * 4];
            float4 kv = *(const float4*)&KT[k][tx * 4];
            a0[0] = fmaf(qv.x, kv.x, a0[0]); a0[1] = fmaf(qv.x, kv.y, a0[1]);
            a0[2] = fmaf(qv.x, kv.z, a0[2]); a0[3] = fmaf(qv.x, kv.w, a0[3]);
            a1[0] = fmaf(qv.y, kv.x, a1[0]); a1[1] = fmaf(qv.y, kv.y, a1[1]);
            a1[2] = fmaf(qv.y, kv.z, a1[2]); a1[3] = fmaf(qv.y, kv.w, a1[3]);
            a2[0] = fmaf(qv.z, kv.x, a2[0]); a2[1] = fmaf(qv.z, kv.y, a2[1]);
            a2[2] = fmaf(qv.z, kv.z, a2[2]); a2[3] = fmaf(qv.z, kv.w, a2[3]);
            a3[0] = fmaf(qv.w, kv.x, a3[0]); a3[1] = fmaf(qv.w, kv.y, a3[1]);
            a3[2] = fmaf(qv.w, kv.z, a3[2]); a3[3] = fmaf(qv.w, kv.w, a3[3]);
        }
        int qg0 = qt * 64 + ty * 4;
        int kg0 = kt * 64 + tx * 4;
        float* Sb = S + ((size_t)bh * SP + qg0) * SP + kg0;
        *(float4*)(Sb + 0 * SP) = make_float4(a0[0], a0[1], a0[2], a0[3]);
        *(float4*)(Sb + 1 * SP) = make_float4(a1[0], a1[1], a1[2], a1[3]);
        *(float4*)(Sb + 2 * SP) = make_float4(a2[0], a2[1], a2[2], a2[3]);
        *(float4*)(Sb + 3 * SP) = make_float4(a3[0], a3[1], a3[2], a3[3]);
    }
}

// ================= PV with fused softmax. grid (16, 6) =================
__global__ __launch_bounds__(256) void attn_pv_sm(const float* __restrict__ S,
                                                  const float* __restrict__ Vp,
                                                  float* __restrict__ O) {
    int bh = blockIdx.x, qt = blockIdx.y;
    int b = bh >> 3, h = bh & 7;
    __shared__ float Pt[64][65];
    __shared__ float Vt[64][32];
    __shared__ float smi[64][2];
    int t = threadIdx.x;
    {
        int r = t >> 2, cg = t & 3;
        const float* row = S + ((size_t)bh * SP + qt * 64 + r) * SP;
        float m = -1e30f;
        for (int i = 0; i < 84; ++i) m = fmaxf(m, row[cg + i * 4]);
        m = fmaxf(m, __shfl_xor(m, 1));
        m = fmaxf(m, __shfl_xor(m, 2));
        float ssum = 0.f;
        for (int i = 0; i < 84; ++i) ssum += expf(row[cg + i * 4] - m);
        ssum += __shfl_xor(ssum, 1);
        ssum += __shfl_xor(ssum, 2);
        if (cg == 0) { smi[r][0] = m; smi[r][1] = 1.f / ssum; }
    }
    __syncthreads();
    int tx = t & 7, ty = t >> 3;
    int d0 = tx * 4, q0 = ty * 2;
    float acc0[4] = {0, 0, 0, 0}, acc1[4] = {0, 0, 0, 0};
    for (int kt = 0; kt < 6; ++kt) {
        __syncthreads();
        #pragma unroll
        for (int s = 0; s < 4; ++s) {
            int idx = t + s * 256;
            int ql = idx >> 4, kk4 = (idx & 15) * 4;
            float4 v = *(const float4*)(S + ((size_t)bh * SP + qt * 64 + ql) * SP + kt * 64 + kk4);
            float m = smi[ql][0], inv = smi[ql][1];
            Pt[ql][kk4 + 0] = expf(v.x - m) * inv;
            Pt[ql][kk4 + 1] = expf(v.y - m) * inv;
            Pt[ql][kk4 + 2] = expf(v.z - m) * inv;
            Pt[ql][kk4 + 3] = expf(v.w - m) * inv;
        }
        #pragma unroll
        for (int s = 0; s < 2; ++s) {
            int idx = t + s * 256;
            int kl = idx >> 3, d4 = (idx & 7) * 4;
            int kg = kt * 64 + kl;
            float4 v = (kg < NQ) ? *(const float4*)(Vp + ((size_t)bh * NQ + kg) * HD + d4)
                                 : make_float4(0.f, 0.f, 0.f, 0.f);
            *(float4*)&Vt[kl][d4] = v;
        }
        __syncthreads();
        #pragma unroll 8
        for (int kk = 0; kk < 64; ++kk) {
            float4 vv = *(const float4*)&Vt[kk][d0];
            float p0 = Pt[q0][kk], p1 = Pt[q0 + 1][kk];
            acc0[0] = fmaf(p0, vv.x, acc0[0]); acc0[1] = fmaf(p0, vv.y, acc0[1]);
            acc0[2] = fmaf(p0, vv.z, acc0[2]); acc0[3] = fmaf(p0, vv.w, acc0[3]);
            acc1[0] = fmaf(p1, vv.x, acc1[0]); acc1[1] = fmaf(p1, vv.y, acc1[1]);
            acc1[2] = fmaf(p1, vv.z, acc1[2]); acc1[3] = fmaf(p1, vv.w, acc1[3]);
        }
    }
    int qg = qt * 64 + q0;
    if (qg < NQ)
        *(float4*)(O + ((size_t)(b * NQ + qg)) * DD + h * HD + d0) =
            make_float4(acc0[0], acc0[1], acc0[2], acc0[3]);
    if (qg + 1 < NQ)
        *(float4*)(O + ((size_t)(b * NQ + qg + 1)) * DD + h * HD + d0) =
            make_float4(acc1[0], acc1[1], acc1[2], acc1[3]);
}

// ================= job: row-block GEMM(K=256,N=256) + residual + LN =================
__device__ __forceinline__ void job_gemm_ln(float* sm, int r0,
                                            const float* __restrict__ A,
                                            const float* __restrict__ Wt,
                                            const float* __restrict__ bias,
                                            const float* __restrict__ gam,
                                            const float* __restrict__ bet,
                                            float* __restrict__ x) {
    float* sA    = sm;          // 1024
    float* redS  = sm + 1024;   // 16
    float* redS2 = sm + 1040;   // 16
    float* mu    = sm + 1056;   // 4
    float* ri    = sm + 1060;   // 4
    int j = threadIdx.x;
    ((float4*)sA)[j] = ((const float4*)(A + (size_t)r0 * DD))[j];
    __syncthreads();
    float acc0 = bias[j], acc1 = acc0, acc2 = acc0, acc3 = acc0;
    const float* wp = Wt + (size_t)j * DD;
    for (int k = 0; k < DD; k += 4) {
        float4 w  = *(const float4*)(wp + k);
        float4 a0 = *(const float4*)(sA + 0 * DD + k);
        float4 a1 = *(const float4*)(sA + 1 * DD + k);
        float4 a2 = *(const float4*)(sA + 2 * DD + k);
        float4 a3 = *(const float4*)(sA + 3 * DD + k);
        acc0 = fmaf(a0.x, w.x, acc0); acc0 = fmaf(a0.y, w.y, acc0); acc0 = fmaf(a0.z, w.z, acc0); acc0 = fmaf(a0.w, w.w, acc0);
        acc1 = fmaf(a1.x, w.x, acc1); acc1 = fmaf(a1.y, w.y, acc1); acc1 = fmaf(a1.z, w.z, acc1); acc1 = fmaf(a1.w, w.w, acc1);
        acc2 = fmaf(a2.x, w.x, acc2); acc2 = fmaf(a2.y, w.y, acc2); acc2 = fmaf(a2.z, w.z, acc2); acc2 = fmaf(a2.w, w.w, acc2);
        acc3 = fmaf(a3.x, w.x, acc3); acc3 = fmaf(a3.y, w.y, acc3); acc3 = fmaf(a3.z, w.z, acc3); acc3 = fmaf(a3.w, w.w, acc3);
    }
    float val[4];
    val[0] = x[(size_t)(r0 + 0) * DD + j] + acc0;
    val[1] = x[(size_t)(r0 + 1) * DD + j] + acc1;
    val[2] = x[(size_t)(r0 + 2) * DD + j] + acc2;
    val[3] = x[(size_t)(r0 + 3) * DD + j] + acc3;
    float s[4], s2[4];
    #pragma unroll
    for (int r = 0; r < 4; ++r) { s[r] = val[r]; s2[r] = val[r] * val[r]; }
    #pragma unroll
    for (int o2 = 32; o2 > 0; o2 >>= 1) {
        #pragma unroll
        for (int r = 0; r < 4; ++r) {
            s[r]  += __shfl_xor(s[r],  o2);
            s2[r] += __shfl_xor(s2[r], o2);
        }
    }
    int wid = j >> 6, lane = j & 63;
    if (lane == 0) {
        #pragma unroll
        for (int r = 0; r < 4; ++r) { redS[r * 4 + wid] = s[r]; redS2[r * 4 + wid] = s2[r]; }
    }
    __syncthreads();
    if (j < 4) {
        int r = j;
        float ts  = redS[r * 4 + 0]  + redS[r * 4 + 1]  + redS[r * 4 + 2]  + redS[r * 4 + 3];
        float ts2 = redS2[r * 4 + 0] + redS2[r * 4 + 1] + redS2[r * 4 + 2] + redS2[r * 4 + 3];
        float mean = ts * (1.f / DD);
        float var = ts2 * (1.f / DD) - mean * mean;
        mu[r] = mean;
        ri[r] = rsqrtf(var + 1e-5f);
    }
    __syncthreads();
    float g = gam[j], be = bet[j];
    #pragma unroll
    for (int r = 0; r < 4; ++r)
        x[(size_t)(r0 + r) * DD + j] = (val[r] - mu[r]) * ri[r] * g + be;
}

// ================= job: sample one row — thread = (view, 8-channel group) =================
// 24 independent float4 gathers per thread; LDS view-reduction.
template <bool TRANSPOSED>
__device__ __forceinline__ void job_sample(float* sm, int row,
                                           const float* __restrict__ f0,
                                           const float* __restrict__ f1,
                                           const float* __restrict__ f2,
                                           const float* __restrict__ refb,
                                           const float* __restrict__ Rm,
                                           const float* __restrict__ Tm,
                                           const float* __restrict__ Km,
                                           float* __restrict__ fused) {
    float* sg    = sm;           // [8][3]
    float* sPart = sm + 32;      // [8][258]
    int t = threadIdx.x;
    int b = row / NQ;
    if (t < 8) {
        int bv = b * VV + t;
        const float* r = refb + (size_t)row * 3;
        const float* R = Rm + (size_t)bv * 9;
        const float* T = Tm + (size_t)bv * 3;
        const float* K = Km + (size_t)bv * 9;
        float p0 = R[0] * r[0] + R[1] * r[1] + R[2] * r[2] + T[0];
        float p1 = R[3] * r[0] + R[4] * r[1] + R[5] * r[2] + T[1];
        float p2 = R[6] * r[0] + R[7] * r[1] + R[8] * r[2] + T[2];
        float z = fmaxf(p2, 0.1f);
        float u  = p0 * K[0] / z + K[2];
        float vv = p1 * K[4] / z + K[5];
        float un = 2.f * u  / (float)(W_IMG - 1) - 1.f;
        float vn = 2.f * vv / (float)(H_IMG - 1) - 1.f;
        bool m = (un > -1.f) && (un < 1.f) && (vn > -1.f) && (vn < 1.f) && (p2 > 0.f);
        sg[t * 3 + 0] = un; sg[t * 3 + 1] = vn; sg[t * 3 + 2] = m ? 1.f : 0.f;
    }
    __syncthreads();
    int v = t >> 5, cg = t & 31;
    int ch0 = cg * 8;
    float acc[8] = {0, 0, 0, 0, 0, 0, 0, 0};
    float m = sg[v * 3 + 2];
    if (m != 0.f) {
        float un = sg[v * 3 + 0], vn = sg[v * 3 + 1];
        int bv = b * VV + v;
        const float* fl[3] = { f0, f1, f2 };
        const int Hs[3] = { 64, 32, 16 };
        #pragma unroll
        for (int lev = 0; lev < 3; ++lev) {
            int Hh = Hs[lev], Ww = Hs[lev];
            const float* f = fl[lev];
            float xx = (un + 1.f) * Ww * 0.5f - 0.5f;
            float yy = (vn + 1.f) * Hh * 0.5f - 0.5f;
            float x0f = floorf(xx), y0f = floorf(yy);
            int ix0 = (int)x0f, iy0 = (int)y0f;
            float wx1 = xx - x0f, wx0 = 1.f - wx1;
            float wy1 = yy - y0f, wy0 = 1.f - wy1;
            #pragma unroll
            for (int tap = 0; tap < 4; ++tap) {
                int ix = ix0 + (tap & 1);
                int iy = iy0 + (tap >> 1);
                float wgt = ((tap & 1) ? wx1 : wx0) * ((tap >> 1) ? wy1 : wy0);
                if (ix >= 0 && ix < Ww && iy >= 0 && iy < Hh) {
                    const float* p;
                    if (TRANSPOSED)
                        p = f + ((size_t)bv * Hh * Ww + (size_t)iy * Ww + ix) * DD + ch0;
                    else
                        p = nullptr;  // untransposed handled below
                    if (TRANSPOSED) {
                        float4 va = *(const float4*)p;
                        float4 vb = *(const float4*)(p + 4);
                        acc[0] = fmaf(wgt, va.x, acc[0]); acc[1] = fmaf(wgt, va.y, acc[1]);
                        acc[2] = fmaf(wgt, va.z, acc[2]); acc[3] = fmaf(wgt, va.w, acc[3]);
                        acc[4] = fmaf(wgt, vb.x, acc[4]); acc[5] = fmaf(wgt, vb.y, acc[5]);
                        acc[6] = fmaf(wgt, vb.z, acc[6]); acc[7] = fmaf(wgt, vb.w, acc[7]);
                    } else {
                        #pragma unroll
                        for (int c = 0; c < 8; ++c) {
                            float vv2 = f[(((size_t)bv * DD + ch0 + c) * Hh + iy) * Ww + ix];
                            acc[c] = fmaf(wgt, vv2, acc[c]);
                        }
                    }
                }
            }
        }
    }
    #pragma unroll
    for (int c = 0; c < 8; ++c) sPart[v * 258 + ch0 + c] = acc[c] * (1.f / 3.f);
    __syncthreads();
    float cnt = sg[2] + sg[5] + sg[8] + sg[11] + sg[14] + sg[17] + sg[20] + sg[23];
    float s = 0.f;
    #pragma unroll
    for (int v2 = 0; v2 < 8; ++v2) s += sPart[v2 * 258 + t];
    fused[(size_t)row * DD + t] = s / fmaxf(cnt, 1.f);
}

// ================= fused dispatch D: oproj+res+LN (168) + sample (672) =================
template <bool TRANSPOSED>
__global__ __launch_bounds__(256) void oproj_sample(const float* __restrict__ attn_o,
                                                    const float* __restrict__ Wo,
                                                    const float* __restrict__ bo,
                                                    const float* __restrict__ gam,
                                                    const float* __restrict__ bet,
                                                    float* __restrict__ x,
                                                    const float* __restrict__ f0,
                                                    const float* __restrict__ f1,
                                                    const float* __restrict__ f2,
                                                    const float* __restrict__ refb,
                                                    const float* __restrict__ Rm,
                                                    const float* __restrict__ Tm,
                                                    const float* __restrict__ Km,
                                                    float* __restrict__ fused) {
    __shared__ float sm[2112];
    if (blockIdx.x < 168)
        job_gemm_ln(sm, blockIdx.x * 4, attn_o, Wo, bo, gam, bet, x);
    else
        job_sample<TRANSPOSED>(sm, blockIdx.x - 168, f0, f1, f2, refb, Rm, Tm, Km, fused);
}

// standalone row-block GEMM + res + LN (proj)
__global__ __launch_bounds__(256) void gemm4_res_ln(const float* __restrict__ A,
                                                    const float* __restrict__ Wt,
                                                    const float* __restrict__ bias,
                                                    const float* __restrict__ gam,
                                                    const float* __restrict__ bet,
                                                    float* __restrict__ x) {
    __shared__ float sm[1064];
    job_gemm_ln(sm, blockIdx.x * 4, A, Wt, bias, gam, bet, x);
}

// ================= generic tiled GEMM. MODE 0 plain, 1 relu. grid (21, N/64, KS) =================
template <int MODE>
__global__ __launch_bounds__(256) void gemm_tile(const float* __restrict__ A,
                                                 const float* __restrict__ W,
                                                 const float* __restrict__ bias,
                                                 float* __restrict__ C,
                                                 int Ktot, int Kper, int Nout) {
    __shared__ float At[32][34];
    __shared__ float Wt[32][68];
    int t = threadIdx.x;
    int m0 = blockIdx.x * 32;
    int n0 = blockIdx.y * 64;
    int kz = blockIdx.z;
    int kofs = kz * Kper;
    int tx = t & 15, ty = t >> 4;
    int nc = n0 + tx * 4;
    float acc0[4], acc1[4];
    {
        float4 bv = make_float4(0.f, 0.f, 0.f, 0.f);
        if (bias && kz == 0) bv = *(const float4*)(bias + nc);
        acc0[0] = bv.x; acc0[1] = bv.y; acc0[2] = bv.z; acc0[3] = bv.w;
        acc1[0] = bv.x; acc1[1] = bv.y; acc1[2] = bv.z; acc1[3] = bv.w;
    }
    int am = t >> 3, ak4 = (t & 7) * 4;
    int ktiles = Kper >> 5;
    for (int kt = 0; kt < ktiles; ++kt) {
        int kk = kofs + kt * 32;
        __syncthreads();
        {
            float4 v = *(const float4*)(A + (size_t)(m0 + am) * Ktot + kk + ak4);
            At[ak4 + 0][am] = v.x; At[ak4 + 1][am] = v.y;
            At[ak4 + 2][am] = v.z; At[ak4 + 3][am] = v.w;
        }
        #pragma unroll
        for (int s = 0; s < 2; ++s) {
            int idx = t + s * 256;
            int wn = idx >> 3, wk4 = (idx & 7) * 4;
            float4 v = *(const float4*)(W + (size_t)(n0 + wn) * Ktot + kk + wk4);
            Wt[wk4 + 0][wn] = v.x; Wt[wk4 + 1][wn] = v.y;
            Wt[wk4 + 2][wn] = v.z; Wt[wk4 + 3][wn] = v.w;
        }
        __syncthreads();
        #pragma unroll
        for (int k = 0; k < 32; ++k) {
            float2 av = *(const float2*)&At[k][ty * 2];
            float4 wv = *(const float4*)&Wt[k][tx * 4];
            acc0[0] = fmaf(av.x, wv.x, acc0[0]); acc0[1] = fmaf(av.x, wv.y, acc0[1]);
            acc0[2] = fmaf(av.x, wv.z, acc0[2]); acc0[3] = fmaf(av.x, wv.w, acc0[3]);
            acc1[0] = fmaf(av.y, wv.x, acc1[0]); acc1[1] = fmaf(av.y, wv.y, acc1[1]);
            acc1[2] = fmaf(av.y, wv.z, acc1[2]); acc1[3] = fmaf(av.y, wv.w, acc1[3]);
        }
    }
    if (MODE == 1) {
        #pragma unroll
        for (int j = 0; j < 4; ++j) { acc0[j] = fmaxf(acc0[j], 0.f); acc1[j] = fmaxf(acc1[j], 0.f); }
    }
    int mr = m0 + ty * 2;
    float* Cb = C + (size_t)kz * MROWS * Nout;
    *(float4*)(Cb + (size_t)mr * Nout + nc)       = make_float4(acc0[0], acc0[1], acc0[2], acc0[3]);
    *(float4*)(Cb + (size_t)(mr + 1) * Nout + nc) = make_float4(acc1[0], acc1[1], acc1[2], acc1[3]);
}

// ================= residual + LN over NP k-split partials; xq = out + qp =================
template <int NP>
__global__ __launch_bounds__(256) void ln_res(float* __restrict__ x,
                                              const float* __restrict__ C,
                                              const float* __restrict__ gam,
                                              const float* __restrict__ bet,
                                              const float* __restrict__ qp,
                                              float* __restrict__ xq) {
    __shared__ float redS[4][4], redS2[4][4];
    __shared__ float mu[4], ri[4];
    int r0 = blockIdx.x * 4;
    int j = threadIdx.x;
    float val[4];
    #pragma unroll
    for (int r = 0; r < 4; ++r) {
        float a = x[(size_t)(r0 + r) * DD + j];
        #pragma unroll
        for (int p = 0; p < NP; ++p) a += C[(size_t)p * MROWS * DD + (size_t)(r0 + r) * DD + j];
        val[r] = a;
    }
    float s[4], s2[4];
    #pragma unroll
    for (int r = 0; r < 4; ++r) { s[r] = val[r]; s2[r] = val[r] * val[r]; }
    #pragma unroll
    for (int o = 32; o > 0; o >>= 1) {
        #pragma unroll
        for (int r = 0; r < 4; ++r) {
            s[r]  += __shfl_xor(s[r],  o);
            s2[r] += __shfl_xor(s2[r], o);
        }
    }
    int wid = j >> 6, lane = j & 63;
    if (lane == 0) {
        #pragma unroll
        for (int r = 0; r < 4; ++r) { redS[r][wid] = s[r]; redS2[r][wid] = s2[r]; }
    }
    __syncthreads();
    if (j < 4) {
        int r = j;
        float ts  = redS[r][0]  + redS[r][1]  + redS[r][2]  + redS[r][3];
        float ts2 = redS2[r][0] + redS2[r][1] + redS2[r][2] + redS2[r][3];
        float mean = ts * (1.f / DD);
        float var = ts2 * (1.f / DD) - mean * mean;
        mu[r] = mean;
        ri[r] = rsqrtf(var + 1e-5f);
    }
    __syncthreads();
    float g = gam[j], be = bet[j];
    #pragma unroll
    for (int r = 0; r < 4; ++r) {
        float o = (val[r] - mu[r]) * ri[r] * g + be;
        x[(size_t)(r0 + r) * DD + j] = o;
        if (qp) xq[(size_t)(r0 + r) * DD + j] = o + qp[(size_t)(r0 + r) * DD + j];
    }
}

extern "C" void kernel_launch(void* const* d_in, const int* in_sizes, int n_in,
                              void* d_out, int out_size, void* d_ws, size_t ws_size,
                              hipStream_t stream) {
    const float* tgt       = (const float*)d_in[0];
    const float* query_pos = (const float*)d_in[1];
    const float* refpts    = (const float*)d_in[2];
    const float* feat0     = (const float*)d_in[3];
    const float* feat1     = (const float*)d_in[4];
    const float* feat2     = (const float*)d_in[5];
    const float* camR      = (const float*)d_in[6];
    const float* camT      = (const float*)d_in[7];
    const float* camK      = (const float*)d_in[8];
    const float* Wqkv      = (const float*)d_in[9];
    const float* bqkv      = (const float*)d_in[10];
    const float* Wo        = (const float*)d_in[11];
    const float* bo        = (const float*)d_in[12];
    const float* ln1_g     = (const float*)d_in[13];
    const float* ln1_b     = (const float*)d_in[14];
    const float* Wproj     = (const float*)d_in[15];
    const float* bproj     = (const float*)d_in[16];
    const float* pn_g      = (const float*)d_in[17];
    const float* pn_b      = (const float*)d_in[18];
    const float* W1        = (const float*)d_in[19];
    const float* b1        = (const float*)d_in[20];
    const float* W2        = (const float*)d_in[21];
    const float* b2        = (const float*)d_in[22];
    const float* ln2_g     = (const float*)d_in[23];
    const float* ln2_b     = (const float*)d_in[24];
    const float* pose_W0   = (const float*)d_in[25];
    const float* pose_b0   = (const float*)d_in[26];
    const float* pose_W1   = (const float*)d_in[27];
    const float* pose_b1   = (const float*)d_in[28];
    const float* pose_W2   = (const float*)d_in[29];
    const float* pose_b2   = (const float*)d_in[30];
    const float* cls_W     = (const float*)d_in[31];
    const float* cls_b     = (const float*)d_in[32];
    float* out = (float*)d_out;

    float* w = (float*)d_ws;
    size_t off = 0;
    auto alloc = [&](size_t n) { float* p = w + off; off += n; return p; };
    float* x      = alloc((size_t)BQ * DD);
    float* xq     = alloc((size_t)BQ * DD);
    float* Qp     = alloc((size_t)BB * HEADS * NQ * HD);
    float* Kp     = alloc((size_t)BB * HEADS * NQ * HD);
    float* Vp     = alloc((size_t)BB * HEADS * NQ * HD);
    float* S      = alloc((size_t)BB * HEADS * SP * SP);
    float* attn_o = alloc((size_t)BQ * DD);
    float* fused  = alloc((size_t)BQ * DD);
    float* ffh    = alloc((size_t)BQ * FF);
    float* ctmp   = alloc((size_t)4 * BQ * DD);
    float* refb   = alloc((size_t)BQ * 3 + 64);
    size_t base_floats = off;
    size_t featT_floats = (size_t)BB * VV * DD * (64 * 64 + 32 * 32 + 16 * 16);
    bool useT = ws_size >= (base_floats + featT_floats) * sizeof(float);
    float *fT0 = nullptr, *fT1 = nullptr, *fT2 = nullptr;
    if (useT) {
        fT0 = alloc((size_t)BB * VV * 64 * 64 * DD);
        fT1 = alloc((size_t)BB * VV * 32 * 32 * DD);
        fT2 = alloc((size_t)BB * VV * 16 * 16 * DD);
    }

    // transpose (5376 blocks, only if useT) + init (168 blocks) in one dispatch
    int tbase = useT ? 5376 : 0;
    transpose_init<<<tbase + 168, 256, 0, stream>>>(feat0, feat1, feat2, fT0, fT1, fT2,
                                                    tgt, query_pos, refpts, x, xq, refb, tbase);

    for (int l = 0; l < NL; ++l) {
        // A: qkv (252 blocks) + pose head of layer l-1 (168 blocks)
        qkv_pose<<<252 + (l > 0 ? 168 : 0), 256, 0, stream>>>(
            xq, x, Wqkv + (size_t)l * 3 * DD * DD, bqkv + (size_t)l * 3 * DD, Qp, Kp, Vp,
            pose_W0, pose_b0, pose_W1, pose_b1, pose_W2, pose_b2, cls_W, cls_b,
            refb, out + (size_t)(l - 1) * BQ * 4);
        attn_scores<<<dim3(BB * HEADS, 6), 256, 0, stream>>>(Qp, Kp, S);
        attn_pv_sm<<<dim3(BB * HEADS, 6), 256, 0, stream>>>(S, Vp, attn_o);
        // D: oproj+res+LN1 (168) + sample (672)
        if (useT)
            oproj_sample<true><<<840, 256, 0, stream>>>(
                attn_o, Wo + (size_t)l * DD * DD, bo + (size_t)l * DD,
                ln1_g + (size_t)l * DD, ln1_b + (size_t)l * DD, x,
                fT0, fT1, fT2, refb, camR, camT, camK, fused);
        else
            oproj_sample<false><<<840, 256, 0, stream>>>(
                attn_o, Wo + (size_t)l * DD * DD, bo + (size_t)l * DD,
                ln1_g + (size_t)l * DD, ln1_b + (size_t)l * DD, x,
                feat0, feat1, feat2, refb, camR, camT, camK, fused);
        // E: proj-GEMM + res + LNpn
        gemm4_res_ln<<<BQ / 4, 256, 0, stream>>>(
            fused, Wproj + (size_t)l * DD * DD, bproj + (size_t)l * DD,
            pn_g + (size_t)l * DD, pn_b + (size_t)l * DD, x);
        // FFN
        gemm_tile<1><<<dim3(21, 16, 1), 256, 0, stream>>>(
            x, W1 + (size_t)l * FF * DD, b1 + (size_t)l * FF, ffh, DD, DD, FF);
        gemm_tile<0><<<dim3(21, 4, 4), 256, 0, stream>>>(
            ffh, W2 + (size_t)l * DD * FF, b2 + (size_t)l * DD, ctmp, FF, FF / 4, DD);
        ln_res<4><<<BQ / 4, 256, 0, stream>>>(
            x, ctmp, ln2_g + (size_t)l * DD, ln2_b + (size_t)l * DD, query_pos, xq);
    }
    // tail: pose head of layer NL-1
    pose_only<<<BQ / 4, 256, 0, stream>>>(
        x, pose_W0, pose_b0, pose_W1, pose_b1, pose_W2, pose_b2, cls_W, cls_b,
        refb, out + (size_t)(NL - 1) * BQ * 4);
}